// Round 6
// baseline (555.157 us; speedup 1.0000x reference)
//
#include <hip/hip_runtime.h>
#include <hip/hip_bf16.h>
#include <hip/hip_fp16.h>

#define NNODES 100000
#define NEDGES 1600000
#define FD 128
#define NCLS 40

#define DBIN 16            // dst bins for fill write-locality (6250 nodes -> 3.2 MB bucket window)
#define BINW 6250
#define NW 8               // src windows for aggregate gather-locality (12500 nodes -> 3.2 MB fp16 XW slice)
#define SWIN 12500
#define CAP 16             // slots per (node, src-window); Poisson(2): P(>16) ~ 5e-11 per cell
#define SLOT 128           // NW*CAP ints per node

typedef __attribute__((ext_vector_type(8))) short short8;   // 8 bf16 (4 VGPRs)
typedef __attribute__((ext_vector_type(4))) float floatx4;  // MFMA C/D

__device__ __forceinline__ unsigned short f32_bf16_rn(float f) {
    unsigned u = __builtin_bit_cast(unsigned, f);
    u = u + 0x7fffu + ((u >> 16) & 1u);          // round-to-nearest-even
    return (unsigned short)(u >> 16);
}
__device__ __forceinline__ float bf16_f32(unsigned short h) {
    unsigned u = ((unsigned)h) << 16;
    return __builtin_bit_cast(float, u);
}
// 4 packed halves (int2) -> float4
__device__ __forceinline__ float4 h4_to_f4(int2 p) {
    __half2 a = __builtin_bit_cast(__half2, p.x);
    __half2 b = __builtin_bit_cast(__half2, p.y);
    float2 fa = __half22float2(a), fb = __half22float2(b);
    return make_float4(fa.x, fa.y, fb.x, fb.y);
}

// ---------------------------------------------------------------------------
// pack W (K=128 x ncols fp32) into MFMA B-fragment layout, split bf16 hi/lo.
// Fragment f = ((ko*nt_count + nt)*64 + lane): 16 shorts [hi 0..7 | lo 0..7];
// elem j is B[k=ko*32+(lane>>4)*8+j][col=nt*16+(lane&15)].
__device__ __forceinline__ void pack_one(const float* __restrict__ W, int ncols,
                                         int nt_count, short* __restrict__ out,
                                         int id) {
    int lane = id & 63;
    int nt = (id >> 6) % nt_count;
    int ko = id / (64 * nt_count);
    int col = nt * 16 + (lane & 15);
    int kbase = ko * 32 + (lane >> 4) * 8;
    short* dst = out + (size_t)id * 16;
    #pragma unroll
    for (int j = 0; j < 8; ++j) {
        float v = (col < ncols) ? W[(size_t)(kbase + j) * ncols + col] : 0.f;
        unsigned short h = f32_bf16_rn(v);
        float r = v - bf16_f32(h);
        dst[j] = (short)h;
        dst[8 + j] = (short)f32_bf16_rn(r);
    }
}

// Kernel P: fused prep — pack 3 weights + zero cnt8 + zero hist/base/cursor.
// ids: [0,2048) W1, [2048,4096) W2, [4096,4864) Wout,
//      [4864,204864) cnt8 int4-zero, [204864,204913) control ints zero.
__global__ __launch_bounds__(256) void prep(const float* __restrict__ W1,
                                            const float* __restrict__ W2,
                                            const float* __restrict__ Wout,
                                            short* __restrict__ w1pk,
                                            short* __restrict__ w2pk,
                                            short* __restrict__ wopk,
                                            int* __restrict__ cnt8,
                                            int* __restrict__ ctrl) {
    int id = blockIdx.x * blockDim.x + threadIdx.x;
    if (id < 2048) pack_one(W1, FD, 8, w1pk, id);
    else if (id < 4096) pack_one(W2, FD, 8, w2pk, id - 2048);
    else if (id < 4864) pack_one(Wout, NCLS, 3, wopk, id - 4096);
    else if (id < 204864) ((int4*)cnt8)[id - 4864] = make_int4(0, 0, 0, 0);
    else if (id < 204913) ctrl[id - 204864] = 0;
}

// Kernel H: histogram edges per dst-bin.
__global__ __launch_bounds__(256) void hist_k(const int* __restrict__ dst,
                                              int* __restrict__ hist) {
    __shared__ int lh[DBIN];
    if (threadIdx.x < DBIN) lh[threadIdx.x] = 0;
    __syncthreads();
    for (int e = blockIdx.x * 256 + threadIdx.x; e < NEDGES; e += gridDim.x * 256)
        atomicAdd(&lh[dst[e] / BINW], 1);
    __syncthreads();
    if (threadIdx.x < DBIN) atomicAdd(&hist[threadIdx.x], lh[threadIdx.x]);
}

// Kernel S: exclusive scan (16 values) -> base[17], cursor[16].
__global__ void scan_k(const int* __restrict__ hist, int* __restrict__ base,
                       int* __restrict__ cursor) {
    if (threadIdx.x == 0) {
        int off = 0;
        for (int w = 0; w < DBIN; ++w) {
            base[w] = off; cursor[w] = off; off += hist[w];
        }
        base[DBIN] = off;
    }
}

// Kernel T: scatter edges into dst-bin-grouped array (block-chunked reservations
// -> coalesced-ish writes, 16 global atomics per block).
__global__ __launch_bounds__(256) void scatter_k(const int* __restrict__ src,
                                                 const int* __restrict__ dst,
                                                 int* __restrict__ cursor,
                                                 int2* __restrict__ ebin) {
    __shared__ int lh[DBIN], lbase[DBIN];
    if (threadIdx.x < DBIN) lh[threadIdx.x] = 0;
    __syncthreads();
    int e = blockIdx.x * 256 + threadIdx.x;
    int s = 0, d = 0, bin = 0, rank = 0;
    bool ok = e < NEDGES;
    if (ok) {
        s = src[e]; d = dst[e]; bin = d / BINW;
        rank = atomicAdd(&lh[bin], 1);
    }
    __syncthreads();
    if (threadIdx.x < DBIN && lh[threadIdx.x] > 0)
        lbase[threadIdx.x] = atomicAdd(&cursor[threadIdx.x], lh[threadIdx.x]);
    __syncthreads();
    if (ok) ebin[lbase[bin] + rank] = make_int2(s, d);
}

// Kernel F: fill one dst-bin. Writes confined to a 3.2 MB L2-resident bucket
// window; scans only this bin's ~100k edges (vs 1.6M in the old 8-pass scan).
// Also bins each neighbor by src-window for aggregate gather locality.
// cnt8[node][w] keeps the TRUE per-window count (bucket writes capped at CAP).
__global__ __launch_bounds__(256) void fill_bin(const int2* __restrict__ ebin,
                                                const int* __restrict__ base,
                                                int* __restrict__ cnt8,
                                                int* __restrict__ bucket,
                                                int bin) {
    int lo = base[bin], hi = base[bin + 1];
    int idx = lo + blockIdx.x * 256 + threadIdx.x;
    if (idx >= hi) return;
    int2 e = ebin[idx];
    int wsrc = e.x / SWIN;
    int pos = atomicAdd(&cnt8[e.y * NW + wsrc], 1);
    if (pos < CAP) bucket[e.y * SLOT + wsrc * CAP + pos] = e.x;
}

// Kernel D: dinv = rsqrt(true_deg + 1); true_deg = sum of 8 window counts.
__global__ __launch_bounds__(256) void compute_dinv(const int* __restrict__ cnt8,
                                                    float* __restrict__ dinv) {
    int i = blockIdx.x * blockDim.x + threadIdx.x;
    if (i >= NNODES) return;
    const int4* c4 = (const int4*)(cnt8 + i * NW);
    int4 a = c4[0], b = c4[1];
    int deg = a.x + a.y + a.z + a.w + b.x + b.y + b.z + b.w;
    dinv[i] = rsqrtf((float)deg + 1.0f);
}

// ---------------------------------------------------------------------------
// Kernel G: Y[N,128] = X[N,128] @ W[128,128] via split-bf16 MFMA (hi*hi +
// hi*lo + lo*hi; missing lo*lo ~2^-18 rel). Output FP16 (aggregate payload).
// A layout: A[m=lane&15][k=quad*8+j]; C/D: col=lane&15, row=quad*4+reg.
__global__ __launch_bounds__(256) void gemm_mfma128_h(const float* __restrict__ X,
                                                      const short* __restrict__ Bpk,
                                                      __half* __restrict__ Y) {
    int w = threadIdx.x >> 6, lane = threadIdx.x & 63;
    int quad = lane >> 4, m = lane & 15;
    int row0 = blockIdx.x * 64 + w * 16;
    int arow = row0 + m;
    bool aok = arow < NNODES;
    floatx4 acc[8];
    #pragma unroll
    for (int nt = 0; nt < 8; ++nt) acc[nt] = (floatx4){0.f, 0.f, 0.f, 0.f};
    #pragma unroll
    for (int ko = 0; ko < 4; ++ko) {
        int kbase = ko * 32 + quad * 8;
        float4 a0 = aok ? *(const float4*)(X + (size_t)arow * FD + kbase)
                        : make_float4(0.f, 0.f, 0.f, 0.f);
        float4 a1 = aok ? *(const float4*)(X + (size_t)arow * FD + kbase + 4)
                        : make_float4(0.f, 0.f, 0.f, 0.f);
        float f[8] = {a0.x, a0.y, a0.z, a0.w, a1.x, a1.y, a1.z, a1.w};
        short8 ahi, alo;
        #pragma unroll
        for (int j = 0; j < 8; ++j) {
            unsigned short h = f32_bf16_rn(f[j]);
            ahi[j] = (short)h;
            alo[j] = (short)f32_bf16_rn(f[j] - bf16_f32(h));
        }
        const short* bp = Bpk + (size_t)(ko * 8) * 64 * 16 + (size_t)lane * 16;
        #pragma unroll
        for (int nt = 0; nt < 8; ++nt) {
            short8 bhi = *(const short8*)bp;
            short8 blo = *(const short8*)(bp + 8);
            bp += 64 * 16;
            acc[nt] = __builtin_amdgcn_mfma_f32_16x16x32_bf16(ahi, bhi, acc[nt], 0, 0, 0);
            acc[nt] = __builtin_amdgcn_mfma_f32_16x16x32_bf16(ahi, blo, acc[nt], 0, 0, 0);
            acc[nt] = __builtin_amdgcn_mfma_f32_16x16x32_bf16(alo, bhi, acc[nt], 0, 0, 0);
        }
    }
    #pragma unroll
    for (int r = 0; r < 4; ++r) {
        int rr = row0 + quad * 4 + r;
        if (rr < NNODES) {
            __half* y = Y + (size_t)rr * FD + m;
            #pragma unroll
            for (int nt = 0; nt < 8; ++nt) y[nt * 16] = __float2half(acc[nt][r]);
        }
    }
}

// ---------------------------------------------------------------------------
// Kernel O: OUT[N,40] = H[N,128] @ Wout[128,40] + bout, fp32 in/out, 3 n-tiles.
__global__ __launch_bounds__(256) void gemm_out_mfma(const float* __restrict__ X,
                                                     const short* __restrict__ Bpk,
                                                     const float* __restrict__ bout,
                                                     float* __restrict__ Y) {
    int w = threadIdx.x >> 6, lane = threadIdx.x & 63;
    int quad = lane >> 4, m = lane & 15;
    int row0 = blockIdx.x * 64 + w * 16;
    int arow = row0 + m;
    bool aok = arow < NNODES;
    floatx4 acc[3];
    #pragma unroll
    for (int nt = 0; nt < 3; ++nt) acc[nt] = (floatx4){0.f, 0.f, 0.f, 0.f};
    #pragma unroll
    for (int ko = 0; ko < 4; ++ko) {
        int kbase = ko * 32 + quad * 8;
        float4 a0 = aok ? *(const float4*)(X + (size_t)arow * FD + kbase)
                        : make_float4(0.f, 0.f, 0.f, 0.f);
        float4 a1 = aok ? *(const float4*)(X + (size_t)arow * FD + kbase + 4)
                        : make_float4(0.f, 0.f, 0.f, 0.f);
        float f[8] = {a0.x, a0.y, a0.z, a0.w, a1.x, a1.y, a1.z, a1.w};
        short8 ahi, alo;
        #pragma unroll
        for (int j = 0; j < 8; ++j) {
            unsigned short h = f32_bf16_rn(f[j]);
            ahi[j] = (short)h;
            alo[j] = (short)f32_bf16_rn(f[j] - bf16_f32(h));
        }
        const short* bp = Bpk + (size_t)(ko * 3) * 64 * 16 + (size_t)lane * 16;
        #pragma unroll
        for (int nt = 0; nt < 3; ++nt) {
            short8 bhi = *(const short8*)bp;
            short8 blo = *(const short8*)(bp + 8);
            bp += 64 * 16;
            acc[nt] = __builtin_amdgcn_mfma_f32_16x16x32_bf16(ahi, bhi, acc[nt], 0, 0, 0);
            acc[nt] = __builtin_amdgcn_mfma_f32_16x16x32_bf16(ahi, blo, acc[nt], 0, 0, 0);
            acc[nt] = __builtin_amdgcn_mfma_f32_16x16x32_bf16(alo, bhi, acc[nt], 0, 0, 0);
        }
    }
    #pragma unroll
    for (int r = 0; r < 4; ++r) {
        int rr = row0 + quad * 4 + r;
        if (rr < NNODES) {
            #pragma unroll
            for (int nt = 0; nt < 3; ++nt) {
                int col = nt * 16 + m;
                if (col < NCLS)
                    Y[(size_t)rr * NCLS + col] = acc[nt][r] + bout[col];
            }
        }
    }
}

// ---------------------------------------------------------------------------
// Kernel A: gather aggregation + bias + ReLU, FP16 payload, SRC-WINDOW-ORDERED
// gathers: staging compacts the 8 per-window lists into one contiguous list in
// window order, so concurrent blocks gather from the same ~3.2 MB XW slice
// (L2-resident) instead of uniformly from 25.6 MB. Main loop identical to R5.
__global__ __launch_bounds__(128) void aggregate_h(const int2* __restrict__ XW2,
                                                   const int* __restrict__ cnt8,
                                                   const int* __restrict__ bucket,
                                                   const float* __restrict__ dinv,
                                                   const float* __restrict__ bias,
                                                   float4* __restrict__ Y4) {
    __shared__ int ssrc[4][SLOT];
    __shared__ float scoef[4][SLOT];
    __shared__ int rawc[4][NW];
    __shared__ int offs[4][NW + 1];
    int sub  = threadIdx.x >> 5;
    int lane = threadIdx.x & 31;
    int node = blockIdx.x * 4 + sub;
    float di = dinv[node];
    if (lane < NW) {
        int c = cnt8[node * NW + lane];
        rawc[sub][lane] = (c > CAP) ? CAP : c;
    }
    __syncthreads();
    if (lane == 0) {
        int off = 0;
        #pragma unroll
        for (int w = 0; w < NW; ++w) { offs[sub][w] = off; off += rawc[sub][w]; }
        offs[sub][NW] = off;
    }
    __syncthreads();
    // compact, window-ordered staging
    #pragma unroll
    for (int w = 0; w < NW; ++w) {
        int s0 = offs[sub][w], cw = rawc[sub][w];
        if (lane < cw) {
            int s = bucket[node * SLOT + w * CAP + lane];
            ssrc[sub][s0 + lane] = s;
            scoef[sub][s0 + lane] = dinv[s] * di;
        }
    }
    __syncthreads();
    int deg = offs[sub][NW];
    float4 b = *(const float4*)(bias + 4 * lane);
    float4 v = h4_to_f4(XW2[(size_t)node * 32 + lane]);
    float sd = di * di;
    float4 acc;
    acc.x = v.x * sd; acc.y = v.y * sd; acc.z = v.z * sd; acc.w = v.w * sd;
    int j = 0;
    for (; j + 3 < deg; j += 4) {           // 4 independent gathers in flight
        int2 p0 = XW2[(size_t)ssrc[sub][j]     * 32 + lane];
        int2 p1 = XW2[(size_t)ssrc[sub][j + 1] * 32 + lane];
        int2 p2 = XW2[(size_t)ssrc[sub][j + 2] * 32 + lane];
        int2 p3 = XW2[(size_t)ssrc[sub][j + 3] * 32 + lane];
        float c0 = scoef[sub][j], c1 = scoef[sub][j + 1];
        float c2 = scoef[sub][j + 2], c3 = scoef[sub][j + 3];
        float4 v0 = h4_to_f4(p0), v1 = h4_to_f4(p1);
        float4 v2 = h4_to_f4(p2), v3 = h4_to_f4(p3);
        acc.x = fmaf(v0.x, c0, acc.x); acc.y = fmaf(v0.y, c0, acc.y);
        acc.z = fmaf(v0.z, c0, acc.z); acc.w = fmaf(v0.w, c0, acc.w);
        acc.x = fmaf(v1.x, c1, acc.x); acc.y = fmaf(v1.y, c1, acc.y);
        acc.z = fmaf(v1.z, c1, acc.z); acc.w = fmaf(v1.w, c1, acc.w);
        acc.x = fmaf(v2.x, c2, acc.x); acc.y = fmaf(v2.y, c2, acc.y);
        acc.z = fmaf(v2.z, c2, acc.z); acc.w = fmaf(v2.w, c2, acc.w);
        acc.x = fmaf(v3.x, c3, acc.x); acc.y = fmaf(v3.y, c3, acc.y);
        acc.z = fmaf(v3.z, c3, acc.z); acc.w = fmaf(v3.w, c3, acc.w);
    }
    for (; j < deg; ++j) {
        float4 v0 = h4_to_f4(XW2[(size_t)ssrc[sub][j] * 32 + lane]);
        float c0 = scoef[sub][j];
        acc.x = fmaf(v0.x, c0, acc.x); acc.y = fmaf(v0.y, c0, acc.y);
        acc.z = fmaf(v0.z, c0, acc.z); acc.w = fmaf(v0.w, c0, acc.w);
    }
    acc.x = fmaxf(acc.x + b.x, 0.f);
    acc.y = fmaxf(acc.y + b.y, 0.f);
    acc.z = fmaxf(acc.z + b.z, 0.f);
    acc.w = fmaxf(acc.w + b.w, 0.f);
    Y4[(size_t)node * 32 + lane] = acc;
}

// ---------------------------------------------------------------------------
extern "C" void kernel_launch(void* const* d_in, const int* in_sizes, int n_in,
                              void* d_out, int out_size, void* d_ws, size_t ws_size,
                              hipStream_t stream) {
    const float* x    = (const float*)d_in[0];
    const int*   ei   = (const int*)d_in[1];     // [2, E] flat: src then dst
    const float* W1   = (const float*)d_in[2];
    const float* b1   = (const float*)d_in[3];
    const float* W2   = (const float*)d_in[4];
    const float* b2   = (const float*)d_in[5];
    const float* Wout = (const float*)d_in[6];
    const float* bout = (const float*)d_in[7];
    float* out = (float*)d_out;

    const int* srcv = ei;
    const int* dstv = ei + NEDGES;

    // workspace layout (~157.5 MB)
    float* bufA   = (float*)d_ws;                        // N*128 f32; fp16 XW; ebin overlays pre-gemm1
    float* bufB   = bufA + (size_t)NNODES * FD;          // N*128 f32
    int*   bucket = (int*)(bufB + (size_t)NNODES * FD);  // N*SLOT ints (51.2 MB)
    int*   cnt8   = bucket + (size_t)NNODES * SLOT;      // N*8 ints (3.2 MB)
    float* dinv   = (float*)(cnt8 + (size_t)NNODES * NW);// N f32
    short* w1pk   = (short*)(dinv + NNODES);             // 2048*16 shorts
    short* w2pk   = w1pk + 2048 * 16;
    short* wopk   = w2pk + 2048 * 16;                    // 768*16 shorts
    int*   hist   = (int*)(wopk + 768 * 16);             // 16
    int*   base   = hist + DBIN;                         // 17
    int*   cursor = base + DBIN + 1;                     // 16
    int2*  ebin   = (int2*)bufA;                         // 1.6M int2 (12.8 MB), dead after fill
    __half* xwh   = (__half*)bufA;

    // prep: pack weights + zero cnt8/ctrl  (ctrl = hist..cursor, 49 ints)
    prep<<<801, 256, 0, stream>>>(W1, W2, Wout, w1pk, w2pk, wopk, cnt8, hist);

    // bin edges by dst-window, then fill one L2-resident window per dispatch
    hist_k<<<1024, 256, 0, stream>>>(dstv, hist);
    scan_k<<<1, 64, 0, stream>>>(hist, base, cursor);
    scatter_k<<<(NEDGES + 255) / 256, 256, 0, stream>>>(srcv, dstv, cursor, ebin);
    for (int bin = 0; bin < DBIN; ++bin)
        fill_bin<<<430, 256, 0, stream>>>(ebin, base, cnt8, bucket, bin);

    compute_dinv<<<(NNODES + 255) / 256, 256, 0, stream>>>(cnt8, dinv);

    const int gblocks = (NNODES + 63) / 64;
    // layer 1
    gemm_mfma128_h<<<gblocks, 256, 0, stream>>>(x, w1pk, xwh);
    aggregate_h<<<NNODES / 4, 128, 0, stream>>>((const int2*)xwh, cnt8, bucket,
                                                dinv, b1, (float4*)bufB);
    // layer 2
    gemm_mfma128_h<<<gblocks, 256, 0, stream>>>(bufB, w2pk, xwh);
    aggregate_h<<<NNODES / 4, 128, 0, stream>>>((const int2*)xwh, cnt8, bucket,
                                                dinv, b2, (float4*)bufB);
    // head
    gemm_out_mfma<<<gblocks, 256, 0, stream>>>(bufB, wopk, bout, out);
}

// Round 7
// 485.834 us; speedup vs baseline: 1.1427x; 1.1427x over previous
//
#include <hip/hip_runtime.h>
#include <hip/hip_bf16.h>
#include <hip/hip_fp16.h>

#define NNODES 100000
#define NEDGES 1600000
#define FD 128
#define NCLS 40
#define MAXDEG 64
#define DBIN 32                     // dst bins; bin window = 3125 nodes -> 0.8 MB bucket region
#define BINW ((NNODES + DBIN - 1) / DBIN)   // 3125

typedef __attribute__((ext_vector_type(8))) short short8;   // 8 bf16 (4 VGPRs)
typedef __attribute__((ext_vector_type(4))) float floatx4;  // MFMA C/D

__device__ __forceinline__ unsigned short f32_bf16_rn(float f) {
    unsigned u = __builtin_bit_cast(unsigned, f);
    u = u + 0x7fffu + ((u >> 16) & 1u);          // round-to-nearest-even
    return (unsigned short)(u >> 16);
}
__device__ __forceinline__ float bf16_f32(unsigned short h) {
    unsigned u = ((unsigned)h) << 16;
    return __builtin_bit_cast(float, u);
}
// 4 packed halves (int2) -> float4
__device__ __forceinline__ float4 h4_to_f4(int2 p) {
    __half2 a = __builtin_bit_cast(__half2, p.x);
    __half2 b = __builtin_bit_cast(__half2, p.y);
    float2 fa = __half22float2(a), fb = __half22float2(b);
    return make_float4(fa.x, fa.y, fb.x, fb.y);
}

// ---------------------------------------------------------------------------
// pack W (K=128 x ncols fp32) into MFMA B-fragment layout, split bf16 hi/lo.
__device__ __forceinline__ void pack_one(const float* __restrict__ W, int ncols,
                                         int nt_count, short* __restrict__ out,
                                         int id) {
    int lane = id & 63;
    int nt = (id >> 6) % nt_count;
    int ko = id / (64 * nt_count);
    int col = nt * 16 + (lane & 15);
    int kbase = ko * 32 + (lane >> 4) * 8;
    short* dst = out + (size_t)id * 16;
    #pragma unroll
    for (int j = 0; j < 8; ++j) {
        float v = (col < ncols) ? W[(size_t)(kbase + j) * ncols + col] : 0.f;
        unsigned short h = f32_bf16_rn(v);
        float r = v - bf16_f32(h);
        dst[j] = (short)h;
        dst[8 + j] = (short)f32_bf16_rn(r);
    }
}

// Kernel P: fused prep — pack 3 weights + zero cnt + zero hist/base/cursor.
// ids: [0,2048) W1, [2048,4096) W2, [4096,4864) Wout,
//      [4864,29864) cnt int4-zero (100000 ints), [29864,29961) ctrl zero (97).
__global__ __launch_bounds__(256) void prep(const float* __restrict__ W1,
                                            const float* __restrict__ W2,
                                            const float* __restrict__ Wout,
                                            short* __restrict__ w1pk,
                                            short* __restrict__ w2pk,
                                            short* __restrict__ wopk,
                                            int* __restrict__ cnt,
                                            int* __restrict__ ctrl) {
    int id = blockIdx.x * blockDim.x + threadIdx.x;
    if (id < 2048) pack_one(W1, FD, 8, w1pk, id);
    else if (id < 4096) pack_one(W2, FD, 8, w2pk, id - 2048);
    else if (id < 4864) pack_one(Wout, NCLS, 3, wopk, id - 4096);
    else if (id < 29864) ((int4*)cnt)[id - 4864] = make_int4(0, 0, 0, 0);
    else if (id < 29961) ctrl[id - 29864] = 0;
}

// Kernel H: histogram edges per dst-bin (LDS-staged).
__global__ __launch_bounds__(256) void hist_k(const int* __restrict__ dst,
                                              int* __restrict__ hist) {
    __shared__ int lh[DBIN];
    if (threadIdx.x < DBIN) lh[threadIdx.x] = 0;
    __syncthreads();
    for (int e = blockIdx.x * 256 + threadIdx.x; e < NEDGES; e += gridDim.x * 256)
        atomicAdd(&lh[dst[e] / BINW], 1);
    __syncthreads();
    if (threadIdx.x < DBIN) atomicAdd(&hist[threadIdx.x], lh[threadIdx.x]);
}

// Kernel S: exclusive scan (DBIN values) -> base[DBIN+1], cursor[DBIN].
__global__ void scan_k(const int* __restrict__ hist, int* __restrict__ base,
                       int* __restrict__ cursor) {
    if (threadIdx.x == 0) {
        int off = 0;
        for (int w = 0; w < DBIN; ++w) {
            base[w] = off; cursor[w] = off; off += hist[w];
        }
        base[DBIN] = off;
    }
}

// Kernel T: scatter edges into dst-bin-grouped array (block-chunked
// reservations -> DBIN global atomics per block, chunk-contiguous writes).
__global__ __launch_bounds__(256) void scatter_k(const int* __restrict__ src,
                                                 const int* __restrict__ dst,
                                                 int* __restrict__ cursor,
                                                 int2* __restrict__ ebin) {
    __shared__ int lh[DBIN], lbase[DBIN];
    if (threadIdx.x < DBIN) lh[threadIdx.x] = 0;
    __syncthreads();
    int e = blockIdx.x * 256 + threadIdx.x;
    int s = 0, d = 0, bin = 0, rank = 0;
    bool ok = e < NEDGES;
    if (ok) {
        s = src[e]; d = dst[e]; bin = d / BINW;
        rank = atomicAdd(&lh[bin], 1);
    }
    __syncthreads();
    if (threadIdx.x < DBIN && lh[threadIdx.x] > 0)
        lbase[threadIdx.x] = atomicAdd(&cursor[threadIdx.x], lh[threadIdx.x]);
    __syncthreads();
    if (ok) ebin[lbase[bin] + rank] = make_int2(s, d);
}

// Kernel F: single-dispatch bucket fill over the BIN-ORDERED edge array.
// Consecutive blocks process consecutive bins (block scheduling ~ blockIdx
// order), so bucket writes are temporally confined to a small sliding dst
// window -> L2 write-coalescing without 8x edge re-scans or 16 launches.
// cnt[] holds the TRUE degree; bucket writes capped at MAXDEG.
__global__ __launch_bounds__(256) void fill_all(const int2* __restrict__ ebin,
                                                int* __restrict__ cnt,
                                                int* __restrict__ bucket) {
    int idx = blockIdx.x * 256 + threadIdx.x;
    if (idx >= NEDGES) return;
    int2 e = ebin[idx];
    int pos = atomicAdd(&cnt[e.y], 1);
    if (pos < MAXDEG) bucket[e.y * MAXDEG + pos] = e.x;
}

// Kernel D: dinv = rsqrt(deg + 1)  (self-loop included)
__global__ __launch_bounds__(256) void compute_dinv(const int* __restrict__ cnt,
                                                    float* __restrict__ dinv) {
    int i = blockIdx.x * blockDim.x + threadIdx.x;
    if (i < NNODES) dinv[i] = rsqrtf((float)cnt[i] + 1.0f);
}

// ---------------------------------------------------------------------------
// Kernel G: Y[N,128] = X[N,128] @ W[128,128] via split-bf16 MFMA (hi*hi +
// hi*lo + lo*hi; missing lo*lo ~2^-18 rel). Output FP16 (aggregate payload).
// A layout: A[m=lane&15][k=quad*8+j]; C/D: col=lane&15, row=quad*4+reg.
__global__ __launch_bounds__(256) void gemm_mfma128_h(const float* __restrict__ X,
                                                      const short* __restrict__ Bpk,
                                                      __half* __restrict__ Y) {
    int w = threadIdx.x >> 6, lane = threadIdx.x & 63;
    int quad = lane >> 4, m = lane & 15;
    int row0 = blockIdx.x * 64 + w * 16;
    int arow = row0 + m;
    bool aok = arow < NNODES;
    floatx4 acc[8];
    #pragma unroll
    for (int nt = 0; nt < 8; ++nt) acc[nt] = (floatx4){0.f, 0.f, 0.f, 0.f};
    #pragma unroll
    for (int ko = 0; ko < 4; ++ko) {
        int kbase = ko * 32 + quad * 8;
        float4 a0 = aok ? *(const float4*)(X + (size_t)arow * FD + kbase)
                        : make_float4(0.f, 0.f, 0.f, 0.f);
        float4 a1 = aok ? *(const float4*)(X + (size_t)arow * FD + kbase + 4)
                        : make_float4(0.f, 0.f, 0.f, 0.f);
        float f[8] = {a0.x, a0.y, a0.z, a0.w, a1.x, a1.y, a1.z, a1.w};
        short8 ahi, alo;
        #pragma unroll
        for (int j = 0; j < 8; ++j) {
            unsigned short h = f32_bf16_rn(f[j]);
            ahi[j] = (short)h;
            alo[j] = (short)f32_bf16_rn(f[j] - bf16_f32(h));
        }
        const short* bp = Bpk + (size_t)(ko * 8) * 64 * 16 + (size_t)lane * 16;
        #pragma unroll
        for (int nt = 0; nt < 8; ++nt) {
            short8 bhi = *(const short8*)bp;
            short8 blo = *(const short8*)(bp + 8);
            bp += 64 * 16;
            acc[nt] = __builtin_amdgcn_mfma_f32_16x16x32_bf16(ahi, bhi, acc[nt], 0, 0, 0);
            acc[nt] = __builtin_amdgcn_mfma_f32_16x16x32_bf16(ahi, blo, acc[nt], 0, 0, 0);
            acc[nt] = __builtin_amdgcn_mfma_f32_16x16x32_bf16(alo, bhi, acc[nt], 0, 0, 0);
        }
    }
    #pragma unroll
    for (int r = 0; r < 4; ++r) {
        int rr = row0 + quad * 4 + r;
        if (rr < NNODES) {
            __half* y = Y + (size_t)rr * FD + m;
            #pragma unroll
            for (int nt = 0; nt < 8; ++nt) y[nt * 16] = __float2half(acc[nt][r]);
        }
    }
}

// ---------------------------------------------------------------------------
// Kernel O: OUT[N,40] = H[N,128] @ Wout[128,40] + bout, fp32 in/out, 3 n-tiles.
__global__ __launch_bounds__(256) void gemm_out_mfma(const float* __restrict__ X,
                                                     const short* __restrict__ Bpk,
                                                     const float* __restrict__ bout,
                                                     float* __restrict__ Y) {
    int w = threadIdx.x >> 6, lane = threadIdx.x & 63;
    int quad = lane >> 4, m = lane & 15;
    int row0 = blockIdx.x * 64 + w * 16;
    int arow = row0 + m;
    bool aok = arow < NNODES;
    floatx4 acc[3];
    #pragma unroll
    for (int nt = 0; nt < 3; ++nt) acc[nt] = (floatx4){0.f, 0.f, 0.f, 0.f};
    #pragma unroll
    for (int ko = 0; ko < 4; ++ko) {
        int kbase = ko * 32 + quad * 8;
        float4 a0 = aok ? *(const float4*)(X + (size_t)arow * FD + kbase)
                        : make_float4(0.f, 0.f, 0.f, 0.f);
        float4 a1 = aok ? *(const float4*)(X + (size_t)arow * FD + kbase + 4)
                        : make_float4(0.f, 0.f, 0.f, 0.f);
        float f[8] = {a0.x, a0.y, a0.z, a0.w, a1.x, a1.y, a1.z, a1.w};
        short8 ahi, alo;
        #pragma unroll
        for (int j = 0; j < 8; ++j) {
            unsigned short h = f32_bf16_rn(f[j]);
            ahi[j] = (short)h;
            alo[j] = (short)f32_bf16_rn(f[j] - bf16_f32(h));
        }
        const short* bp = Bpk + (size_t)(ko * 3) * 64 * 16 + (size_t)lane * 16;
        #pragma unroll
        for (int nt = 0; nt < 3; ++nt) {
            short8 bhi = *(const short8*)bp;
            short8 blo = *(const short8*)(bp + 8);
            bp += 64 * 16;
            acc[nt] = __builtin_amdgcn_mfma_f32_16x16x32_bf16(ahi, bhi, acc[nt], 0, 0, 0);
            acc[nt] = __builtin_amdgcn_mfma_f32_16x16x32_bf16(ahi, blo, acc[nt], 0, 0, 0);
            acc[nt] = __builtin_amdgcn_mfma_f32_16x16x32_bf16(alo, bhi, acc[nt], 0, 0, 0);
        }
    }
    #pragma unroll
    for (int r = 0; r < 4; ++r) {
        int rr = row0 + quad * 4 + r;
        if (rr < NNODES) {
            #pragma unroll
            for (int nt = 0; nt < 3; ++nt) {
                int col = nt * 16 + m;
                if (col < NCLS)
                    Y[(size_t)rr * NCLS + col] = acc[nt][r] + bout[col];
            }
        }
    }
}

// ---------------------------------------------------------------------------
// Kernel A: gather aggregation + bias + ReLU, FP16 payload (R5 structure —
// contiguous 64-slot bucket, arrival-order gathers), widened to 8 gathers in
// flight (R5 VALUBusy 31% / latency headroom; VGPR ~36, occupancy unchanged).
__global__ __launch_bounds__(128) void aggregate_h(const int2* __restrict__ XW2,
                                                   const int* __restrict__ cnt,
                                                   const int* __restrict__ bucket,
                                                   const float* __restrict__ dinv,
                                                   const float* __restrict__ bias,
                                                   float4* __restrict__ Y4) {
    __shared__ int ssrc[4][MAXDEG];
    __shared__ float scoef[4][MAXDEG];
    int sub  = threadIdx.x >> 5;
    int lane = threadIdx.x & 31;
    int node = blockIdx.x * 4 + sub;
    float di = dinv[node];
    int deg = cnt[node];
    if (deg > MAXDEG) deg = MAXDEG;
    for (int j = lane; j < deg; j += 32) {
        int s = bucket[node * MAXDEG + j];
        ssrc[sub][j] = s;
        scoef[sub][j] = dinv[s] * di;
    }
    __syncthreads();
    float4 b = *(const float4*)(bias + 4 * lane);
    float4 v = h4_to_f4(XW2[(size_t)node * 32 + lane]);
    float sd = di * di;
    float4 acc;
    acc.x = v.x * sd; acc.y = v.y * sd; acc.z = v.z * sd; acc.w = v.w * sd;
    int j = 0;
    for (; j + 7 < deg; j += 8) {           // 8 independent gathers in flight
        int2 p[8];
        float c[8];
        #pragma unroll
        for (int q = 0; q < 8; ++q) {
            p[q] = XW2[(size_t)ssrc[sub][j + q] * 32 + lane];
            c[q] = scoef[sub][j + q];
        }
        #pragma unroll
        for (int q = 0; q < 8; ++q) {
            float4 vq = h4_to_f4(p[q]);
            acc.x = fmaf(vq.x, c[q], acc.x); acc.y = fmaf(vq.y, c[q], acc.y);
            acc.z = fmaf(vq.z, c[q], acc.z); acc.w = fmaf(vq.w, c[q], acc.w);
        }
    }
    for (; j < deg; ++j) {
        float4 v0 = h4_to_f4(XW2[(size_t)ssrc[sub][j] * 32 + lane]);
        float c0 = scoef[sub][j];
        acc.x = fmaf(v0.x, c0, acc.x); acc.y = fmaf(v0.y, c0, acc.y);
        acc.z = fmaf(v0.z, c0, acc.z); acc.w = fmaf(v0.w, c0, acc.w);
    }
    acc.x = fmaxf(acc.x + b.x, 0.f);
    acc.y = fmaxf(acc.y + b.y, 0.f);
    acc.z = fmaxf(acc.z + b.z, 0.f);
    acc.w = fmaxf(acc.w + b.w, 0.f);
    Y4[(size_t)node * 32 + lane] = acc;
}

// ---------------------------------------------------------------------------
extern "C" void kernel_launch(void* const* d_in, const int* in_sizes, int n_in,
                              void* d_out, int out_size, void* d_ws, size_t ws_size,
                              hipStream_t stream) {
    const float* x    = (const float*)d_in[0];
    const int*   ei   = (const int*)d_in[1];     // [2, E] flat: src then dst
    const float* W1   = (const float*)d_in[2];
    const float* b1   = (const float*)d_in[3];
    const float* W2   = (const float*)d_in[4];
    const float* b2   = (const float*)d_in[5];
    const float* Wout = (const float*)d_in[6];
    const float* bout = (const float*)d_in[7];
    float* out = (float*)d_out;

    const int* srcv = ei;
    const int* dstv = ei + NEDGES;

    // workspace layout
    float* bufA   = (float*)d_ws;                        // N*128 f32; ebin overlay pre-gemm1; fp16 XW after
    float* bufB   = bufA + (size_t)NNODES * FD;          // N*128 f32
    int*   bucket = (int*)(bufB + (size_t)NNODES * FD);  // N*64 int (25.6 MB)
    int*   cnt    = bucket + (size_t)NNODES * MAXDEG;    // N int
    float* dinv   = (float*)(cnt + NNODES);              // N f32
    short* w1pk   = (short*)(dinv + NNODES);             // 2048*16 shorts
    short* w2pk   = w1pk + 2048 * 16;
    short* wopk   = w2pk + 2048 * 16;                    // 768*16 shorts
    int*   hist   = (int*)(wopk + 768 * 16);             // DBIN
    int*   base   = hist + DBIN;                         // DBIN+1
    int*   cursor = base + DBIN + 1;                     // DBIN
    int2*  ebin   = (int2*)bufA;                         // 1.6M int2 (12.8 MB), dead after fill
    __half* xwh   = (__half*)bufA;

    // prep: pack weights + zero cnt + zero ctrl (hist/base/cursor)
    prep<<<118, 256, 0, stream>>>(W1, W2, Wout, w1pk, w2pk, wopk, cnt, hist);

    // bin edges by dst window once, then one blockIdx-ordered fill
    hist_k<<<1024, 256, 0, stream>>>(dstv, hist);
    scan_k<<<1, 64, 0, stream>>>(hist, base, cursor);
    scatter_k<<<(NEDGES + 255) / 256, 256, 0, stream>>>(srcv, dstv, cursor, ebin);
    fill_all<<<(NEDGES + 255) / 256, 256, 0, stream>>>(ebin, cnt, bucket);

    compute_dinv<<<(NNODES + 255) / 256, 256, 0, stream>>>(cnt, dinv);

    const int gblocks = (NNODES + 63) / 64;
    // layer 1
    gemm_mfma128_h<<<gblocks, 256, 0, stream>>>(x, w1pk, xwh);
    aggregate_h<<<NNODES / 4, 128, 0, stream>>>((const int2*)xwh, cnt, bucket,
                                                dinv, b1, (float4*)bufB);
    // layer 2
    gemm_mfma128_h<<<gblocks, 256, 0, stream>>>(bufB, w2pk, xwh);
    aggregate_h<<<NNODES / 4, 128, 0, stream>>>((const int2*)xwh, cnt, bucket,
                                                dinv, b2, (float4*)bufB);
    // head
    gemm_out_mfma<<<gblocks, 256, 0, stream>>>(bufB, wopk, bout, out);
}

// Round 8
// 405.721 us; speedup vs baseline: 1.3683x; 1.1975x over previous
//
#include <hip/hip_runtime.h>
#include <hip/hip_bf16.h>
#include <hip/hip_fp16.h>

#define NNODES 100000
#define NEDGES 1600000
#define FD 128
#define NCLS 40
#define MAXDEG 64
#define DBIN 16                              // dst bins; window = 6250 nodes -> 1.6 MB bucket region
#define BINW ((NNODES + DBIN - 1) / DBIN)    // 6250
#define CAPB 110000                          // per-bin segment capacity (E/DBIN=100k, +32 sigma)
#define SBLK 4096                            // edges per scatter block

typedef __attribute__((ext_vector_type(8))) short short8;   // 8 bf16 (4 VGPRs)
typedef __attribute__((ext_vector_type(4))) float floatx4;  // MFMA C/D

__device__ __forceinline__ unsigned short f32_bf16_rn(float f) {
    unsigned u = __builtin_bit_cast(unsigned, f);
    u = u + 0x7fffu + ((u >> 16) & 1u);          // round-to-nearest-even
    return (unsigned short)(u >> 16);
}
__device__ __forceinline__ float bf16_f32(unsigned short h) {
    unsigned u = ((unsigned)h) << 16;
    return __builtin_bit_cast(float, u);
}
// 4 packed halves (int2) -> float4
__device__ __forceinline__ float4 h4_to_f4(int2 p) {
    __half2 a = __builtin_bit_cast(__half2, p.x);
    __half2 b = __builtin_bit_cast(__half2, p.y);
    float2 fa = __half22float2(a), fb = __half22float2(b);
    return make_float4(fa.x, fa.y, fb.x, fb.y);
}

// ---------------------------------------------------------------------------
// pack W (K=128 x ncols fp32) into MFMA B-fragment layout, split bf16 hi/lo.
__device__ __forceinline__ void pack_one(const float* __restrict__ W, int ncols,
                                         int nt_count, short* __restrict__ out,
                                         int id) {
    int lane = id & 63;
    int nt = (id >> 6) % nt_count;
    int ko = id / (64 * nt_count);
    int col = nt * 16 + (lane & 15);
    int kbase = ko * 32 + (lane >> 4) * 8;
    short* dst = out + (size_t)id * 16;
    #pragma unroll
    for (int j = 0; j < 8; ++j) {
        float v = (col < ncols) ? W[(size_t)(kbase + j) * ncols + col] : 0.f;
        unsigned short h = f32_bf16_rn(v);
        float r = v - bf16_f32(h);
        dst[j] = (short)h;
        dst[8 + j] = (short)f32_bf16_rn(r);
    }
}

// Kernel P: fused prep — pack 3 weights + zero cnt + init cursors to segment
// bases. ids: [0,2048) W1, [2048,4096) W2, [4096,4864) Wout,
//             [4864,29864) cnt int4-zero, [29864,29880) cursor[i]=i*CAPB.
__global__ __launch_bounds__(256) void prep(const float* __restrict__ W1,
                                            const float* __restrict__ W2,
                                            const float* __restrict__ Wout,
                                            short* __restrict__ w1pk,
                                            short* __restrict__ w2pk,
                                            short* __restrict__ wopk,
                                            int* __restrict__ cnt,
                                            int* __restrict__ cursor) {
    int id = blockIdx.x * blockDim.x + threadIdx.x;
    if (id < 2048) pack_one(W1, FD, 8, w1pk, id);
    else if (id < 4096) pack_one(W2, FD, 8, w2pk, id - 2048);
    else if (id < 4864) pack_one(Wout, NCLS, 3, wopk, id - 4096);
    else if (id < 29864) ((int4*)cnt)[id - 4864] = make_int4(0, 0, 0, 0);
    else if (id < 29880) cursor[id - 29864] = (id - 29864) * CAPB;
}

// Kernel T: one-pass dst-bin partition into fixed-capacity segments.
// 391 blocks x 4096 edges. Per-WAVE LDS histograms (no cross-wave LDS
// contention; ~4 lanes/bin within a wave) and ONE global reservation per
// (block,bin) -> 391*16 = 6.3k global atomics (R7: 200k on 2 cache lines).
__global__ __launch_bounds__(256) void scatter_k(const int* __restrict__ src,
                                                 const int* __restrict__ dst,
                                                 int* __restrict__ cursor,
                                                 int2* __restrict__ ebin) {
    __shared__ int lh[4][DBIN];      // per-wave counts, then per-wave rank cursors
    __shared__ int obase[4][DBIN];   // per-wave write bases
    int t = threadIdx.x, wv = t >> 6;
    int base = blockIdx.x * SBLK;
    if (t < 4 * DBIN) ((int*)lh)[t] = 0;
    __syncthreads();
    int bins[16];
    #pragma unroll
    for (int i = 0; i < 16; ++i) {
        int idx = base + t + i * 256;
        int b = -1;
        if (idx < NEDGES) {
            b = dst[idx] / BINW;
            atomicAdd(&lh[wv][b], 1);
        }
        bins[i] = b;
    }
    __syncthreads();
    if (t < DBIN) {
        int c0 = lh[0][t], c1 = lh[1][t], c2 = lh[2][t], c3 = lh[3][t];
        int g = atomicAdd(&cursor[t], c0 + c1 + c2 + c3);
        obase[0][t] = g;
        obase[1][t] = g + c0;
        obase[2][t] = g + c0 + c1;
        obase[3][t] = g + c0 + c1 + c2;
    }
    __syncthreads();
    if (t < 4 * DBIN) ((int*)lh)[t] = 0;   // reuse as rank counters
    __syncthreads();
    #pragma unroll
    for (int i = 0; i < 16; ++i) {
        int idx = base + t + i * 256;
        if (idx < NEDGES) {
            int b = bins[i];
            int r = atomicAdd(&lh[wv][b], 1);
            int pos = obase[wv][b] + r;
            if (pos < (b + 1) * CAPB)       // statistical OOB guard
                ebin[pos] = make_int2(src[idx], dst[idx]);
        }
    }
}

// Kernel F: bucket fill over the bin-segmented edge array. Consecutive blocks
// process consecutive bins (block scheduling ~ blockIdx order), so bucket
// writes are temporally confined to a 1.6 MB sliding dst window (L2-resident).
// cnt[] holds the TRUE degree; bucket writes capped at MAXDEG.
__global__ __launch_bounds__(256) void fill_all(const int2* __restrict__ ebin,
                                                const int* __restrict__ cursor,
                                                int* __restrict__ cnt,
                                                int* __restrict__ bucket) {
    int idx = blockIdx.x * 256 + threadIdx.x;
    int bin = idx / CAPB;                    // grid covers DBIN*CAPB exactly
    int hi = cursor[bin];
    int cap = (bin + 1) * CAPB;
    if (idx >= (hi < cap ? hi : cap)) return;
    int2 e = ebin[idx];
    int pos = atomicAdd(&cnt[e.y], 1);
    if (pos < MAXDEG) bucket[e.y * MAXDEG + pos] = e.x;
}

// Kernel D: dinv = rsqrt(deg + 1)  (self-loop included)
__global__ __launch_bounds__(256) void compute_dinv(const int* __restrict__ cnt,
                                                    float* __restrict__ dinv) {
    int i = blockIdx.x * blockDim.x + threadIdx.x;
    if (i < NNODES) dinv[i] = rsqrtf((float)cnt[i] + 1.0f);
}

// ---------------------------------------------------------------------------
// Kernel G: Y[N,128] = X[N,128] @ W[128,128] via split-bf16 MFMA (hi*hi +
// hi*lo + lo*hi; missing lo*lo ~2^-18 rel). Output FP16 (aggregate payload).
// A layout: A[m=lane&15][k=quad*8+j]; C/D: col=lane&15, row=quad*4+reg.
__global__ __launch_bounds__(256) void gemm_mfma128_h(const float* __restrict__ X,
                                                      const short* __restrict__ Bpk,
                                                      __half* __restrict__ Y) {
    int w = threadIdx.x >> 6, lane = threadIdx.x & 63;
    int quad = lane >> 4, m = lane & 15;
    int row0 = blockIdx.x * 64 + w * 16;
    int arow = row0 + m;
    bool aok = arow < NNODES;
    floatx4 acc[8];
    #pragma unroll
    for (int nt = 0; nt < 8; ++nt) acc[nt] = (floatx4){0.f, 0.f, 0.f, 0.f};
    #pragma unroll
    for (int ko = 0; ko < 4; ++ko) {
        int kbase = ko * 32 + quad * 8;
        float4 a0 = aok ? *(const float4*)(X + (size_t)arow * FD + kbase)
                        : make_float4(0.f, 0.f, 0.f, 0.f);
        float4 a1 = aok ? *(const float4*)(X + (size_t)arow * FD + kbase + 4)
                        : make_float4(0.f, 0.f, 0.f, 0.f);
        float f[8] = {a0.x, a0.y, a0.z, a0.w, a1.x, a1.y, a1.z, a1.w};
        short8 ahi, alo;
        #pragma unroll
        for (int j = 0; j < 8; ++j) {
            unsigned short h = f32_bf16_rn(f[j]);
            ahi[j] = (short)h;
            alo[j] = (short)f32_bf16_rn(f[j] - bf16_f32(h));
        }
        const short* bp = Bpk + (size_t)(ko * 8) * 64 * 16 + (size_t)lane * 16;
        #pragma unroll
        for (int nt = 0; nt < 8; ++nt) {
            short8 bhi = *(const short8*)bp;
            short8 blo = *(const short8*)(bp + 8);
            bp += 64 * 16;
            acc[nt] = __builtin_amdgcn_mfma_f32_16x16x32_bf16(ahi, bhi, acc[nt], 0, 0, 0);
            acc[nt] = __builtin_amdgcn_mfma_f32_16x16x32_bf16(ahi, blo, acc[nt], 0, 0, 0);
            acc[nt] = __builtin_amdgcn_mfma_f32_16x16x32_bf16(alo, bhi, acc[nt], 0, 0, 0);
        }
    }
    #pragma unroll
    for (int r = 0; r < 4; ++r) {
        int rr = row0 + quad * 4 + r;
        if (rr < NNODES) {
            __half* y = Y + (size_t)rr * FD + m;
            #pragma unroll
            for (int nt = 0; nt < 8; ++nt) y[nt * 16] = __float2half(acc[nt][r]);
        }
    }
}

// ---------------------------------------------------------------------------
// Kernel O: OUT[N,40] = H[N,128] @ Wout[128,40] + bout, fp32 in/out, 3 n-tiles.
__global__ __launch_bounds__(256) void gemm_out_mfma(const float* __restrict__ X,
                                                     const short* __restrict__ Bpk,
                                                     const float* __restrict__ bout,
                                                     float* __restrict__ Y) {
    int w = threadIdx.x >> 6, lane = threadIdx.x & 63;
    int quad = lane >> 4, m = lane & 15;
    int row0 = blockIdx.x * 64 + w * 16;
    int arow = row0 + m;
    bool aok = arow < NNODES;
    floatx4 acc[3];
    #pragma unroll
    for (int nt = 0; nt < 3; ++nt) acc[nt] = (floatx4){0.f, 0.f, 0.f, 0.f};
    #pragma unroll
    for (int ko = 0; ko < 4; ++ko) {
        int kbase = ko * 32 + quad * 8;
        float4 a0 = aok ? *(const float4*)(X + (size_t)arow * FD + kbase)
                        : make_float4(0.f, 0.f, 0.f, 0.f);
        float4 a1 = aok ? *(const float4*)(X + (size_t)arow * FD + kbase + 4)
                        : make_float4(0.f, 0.f, 0.f, 0.f);
        float f[8] = {a0.x, a0.y, a0.z, a0.w, a1.x, a1.y, a1.z, a1.w};
        short8 ahi, alo;
        #pragma unroll
        for (int j = 0; j < 8; ++j) {
            unsigned short h = f32_bf16_rn(f[j]);
            ahi[j] = (short)h;
            alo[j] = (short)f32_bf16_rn(f[j] - bf16_f32(h));
        }
        const short* bp = Bpk + (size_t)(ko * 3) * 64 * 16 + (size_t)lane * 16;
        #pragma unroll
        for (int nt = 0; nt < 3; ++nt) {
            short8 bhi = *(const short8*)bp;
            short8 blo = *(const short8*)(bp + 8);
            bp += 64 * 16;
            acc[nt] = __builtin_amdgcn_mfma_f32_16x16x32_bf16(ahi, bhi, acc[nt], 0, 0, 0);
            acc[nt] = __builtin_amdgcn_mfma_f32_16x16x32_bf16(ahi, blo, acc[nt], 0, 0, 0);
            acc[nt] = __builtin_amdgcn_mfma_f32_16x16x32_bf16(alo, bhi, acc[nt], 0, 0, 0);
        }
    }
    #pragma unroll
    for (int r = 0; r < 4; ++r) {
        int rr = row0 + quad * 4 + r;
        if (rr < NNODES) {
            #pragma unroll
            for (int nt = 0; nt < 3; ++nt) {
                int col = nt * 16 + m;
                if (col < NCLS)
                    Y[(size_t)rr * NCLS + col] = acc[nt][r] + bout[col];
            }
        }
    }
}

// ---------------------------------------------------------------------------
// Kernel A: gather aggregation + bias + ReLU, FP16 payload (R5 structure,
// 8 gathers in flight). L2-miss-path bound at ~199 MB FETCH.
__global__ __launch_bounds__(128) void aggregate_h(const int2* __restrict__ XW2,
                                                   const int* __restrict__ cnt,
                                                   const int* __restrict__ bucket,
                                                   const float* __restrict__ dinv,
                                                   const float* __restrict__ bias,
                                                   float4* __restrict__ Y4) {
    __shared__ int ssrc[4][MAXDEG];
    __shared__ float scoef[4][MAXDEG];
    int sub  = threadIdx.x >> 5;
    int lane = threadIdx.x & 31;
    int node = blockIdx.x * 4 + sub;
    float di = dinv[node];
    int deg = cnt[node];
    if (deg > MAXDEG) deg = MAXDEG;
    for (int j = lane; j < deg; j += 32) {
        int s = bucket[node * MAXDEG + j];
        ssrc[sub][j] = s;
        scoef[sub][j] = dinv[s] * di;
    }
    __syncthreads();
    float4 b = *(const float4*)(bias + 4 * lane);
    float4 v = h4_to_f4(XW2[(size_t)node * 32 + lane]);
    float sd = di * di;
    float4 acc;
    acc.x = v.x * sd; acc.y = v.y * sd; acc.z = v.z * sd; acc.w = v.w * sd;
    int j = 0;
    for (; j + 7 < deg; j += 8) {           // 8 independent gathers in flight
        int2 p[8];
        float c[8];
        #pragma unroll
        for (int q = 0; q < 8; ++q) {
            p[q] = XW2[(size_t)ssrc[sub][j + q] * 32 + lane];
            c[q] = scoef[sub][j + q];
        }
        #pragma unroll
        for (int q = 0; q < 8; ++q) {
            float4 vq = h4_to_f4(p[q]);
            acc.x = fmaf(vq.x, c[q], acc.x); acc.y = fmaf(vq.y, c[q], acc.y);
            acc.z = fmaf(vq.z, c[q], acc.z); acc.w = fmaf(vq.w, c[q], acc.w);
        }
    }
    for (; j < deg; ++j) {
        float4 v0 = h4_to_f4(XW2[(size_t)ssrc[sub][j] * 32 + lane]);
        float c0 = scoef[sub][j];
        acc.x = fmaf(v0.x, c0, acc.x); acc.y = fmaf(v0.y, c0, acc.y);
        acc.z = fmaf(v0.z, c0, acc.z); acc.w = fmaf(v0.w, c0, acc.w);
    }
    acc.x = fmaxf(acc.x + b.x, 0.f);
    acc.y = fmaxf(acc.y + b.y, 0.f);
    acc.z = fmaxf(acc.z + b.z, 0.f);
    acc.w = fmaxf(acc.w + b.w, 0.f);
    Y4[(size_t)node * 32 + lane] = acc;
}

// ---------------------------------------------------------------------------
extern "C" void kernel_launch(void* const* d_in, const int* in_sizes, int n_in,
                              void* d_out, int out_size, void* d_ws, size_t ws_size,
                              hipStream_t stream) {
    const float* x    = (const float*)d_in[0];
    const int*   ei   = (const int*)d_in[1];     // [2, E] flat: src then dst
    const float* W1   = (const float*)d_in[2];
    const float* b1   = (const float*)d_in[3];
    const float* W2   = (const float*)d_in[4];
    const float* b2   = (const float*)d_in[5];
    const float* Wout = (const float*)d_in[6];
    const float* bout = (const float*)d_in[7];
    float* out = (float*)d_out;

    const int* srcv = ei;
    const int* dstv = ei + NEDGES;

    // workspace layout
    float* bufA   = (float*)d_ws;                        // N*128 f32; ebin overlay pre-gemm1; fp16 XW after
    float* bufB   = bufA + (size_t)NNODES * FD;          // N*128 f32
    int*   bucket = (int*)(bufB + (size_t)NNODES * FD);  // N*64 int (25.6 MB)
    int*   cnt    = bucket + (size_t)NNODES * MAXDEG;    // N int
    float* dinv   = (float*)(cnt + NNODES);              // N f32
    short* w1pk   = (short*)(dinv + NNODES);             // 2048*16 shorts
    short* w2pk   = w1pk + 2048 * 16;
    short* wopk   = w2pk + 2048 * 16;                    // 768*16 shorts
    int*   cursor = (int*)(wopk + 768 * 16);             // DBIN
    int2*  ebin   = (int2*)bufA;                         // DBIN*CAPB int2 (14.1 MB), dead after fill
    __half* xwh   = (__half*)bufA;

    // prep: pack weights + zero cnt + init segment cursors
    prep<<<117, 256, 0, stream>>>(W1, W2, Wout, w1pk, w2pk, wopk, cnt, cursor);

    // one-pass dst-bin partition, then blockIdx-ordered fill
    scatter_k<<<(NEDGES + SBLK - 1) / SBLK, 256, 0, stream>>>(srcv, dstv, cursor, ebin);
    fill_all<<<DBIN * CAPB / 256, 256, 0, stream>>>(ebin, cursor, cnt, bucket);

    compute_dinv<<<(NNODES + 255) / 256, 256, 0, stream>>>(cnt, dinv);

    const int gblocks = (NNODES + 63) / 64;
    // layer 1
    gemm_mfma128_h<<<gblocks, 256, 0, stream>>>(x, w1pk, xwh);
    aggregate_h<<<NNODES / 4, 128, 0, stream>>>((const int2*)xwh, cnt, bucket,
                                                dinv, b1, (float4*)bufB);
    // layer 2
    gemm_mfma128_h<<<gblocks, 256, 0, stream>>>(bufB, w2pk, xwh);
    aggregate_h<<<NNODES / 4, 128, 0, stream>>>((const int2*)xwh, cnt, bucket,
                                                dinv, b2, (float4*)bufB);
    // head
    gemm_out_mfma<<<gblocks, 256, 0, stream>>>(bufB, wopk, bout, out);
}

// Round 9
// 348.122 us; speedup vs baseline: 1.5947x; 1.1655x over previous
//
#include <hip/hip_runtime.h>
#include <hip/hip_bf16.h>
#include <hip/hip_fp16.h>

#define NNODES 100000
#define NEDGES 1600000
#define FD 128
#define NCLS 40
#define DEGCAP 128                 // staging cap; Poisson(16): P(deg>128) ~ 1e-50
#define NBIN 256                   // dst bins; 391 nodes/bin
#define BINW2 391                  // NBIN*BINW2 = 100096 >= NNODES
#define CAPB2 8192                 // per-bin edge segment (mean 6250, +24 sigma)
#define SBLK 4096                  // edges per scatter block

typedef __attribute__((ext_vector_type(8))) short short8;   // 8 bf16 (4 VGPRs)
typedef __attribute__((ext_vector_type(4))) float floatx4;  // MFMA C/D

__device__ __forceinline__ unsigned short f32_bf16_rn(float f) {
    unsigned u = __builtin_bit_cast(unsigned, f);
    u = u + 0x7fffu + ((u >> 16) & 1u);          // round-to-nearest-even
    return (unsigned short)(u >> 16);
}
__device__ __forceinline__ float bf16_f32(unsigned short h) {
    unsigned u = ((unsigned)h) << 16;
    return __builtin_bit_cast(float, u);
}
// 4 packed halves (int2) -> float4
__device__ __forceinline__ float4 h4_to_f4(int2 p) {
    __half2 a = __builtin_bit_cast(__half2, p.x);
    __half2 b = __builtin_bit_cast(__half2, p.y);
    float2 fa = __half22float2(a), fb = __half22float2(b);
    return make_float4(fa.x, fa.y, fb.x, fb.y);
}

// ---------------------------------------------------------------------------
// pack W (K=128 x ncols fp32) into MFMA B-fragment layout, split bf16 hi/lo.
__device__ __forceinline__ void pack_one(const float* __restrict__ W, int ncols,
                                         int nt_count, short* __restrict__ out,
                                         int id) {
    int lane = id & 63;
    int nt = (id >> 6) % nt_count;
    int ko = id / (64 * nt_count);
    int col = nt * 16 + (lane & 15);
    int kbase = ko * 32 + (lane >> 4) * 8;
    short* dst = out + (size_t)id * 16;
    #pragma unroll
    for (int j = 0; j < 8; ++j) {
        float v = (col < ncols) ? W[(size_t)(kbase + j) * ncols + col] : 0.f;
        unsigned short h = f32_bf16_rn(v);
        float r = v - bf16_f32(h);
        dst[j] = (short)h;
        dst[8 + j] = (short)f32_bf16_rn(r);
    }
}

// Kernel P: fused prep — pack 3 weights + init the 256 bin cursors.
// ids: [0,2048) W1, [2048,4096) W2, [4096,4864) Wout, [4864,5120) cursor.
__global__ __launch_bounds__(256) void prep(const float* __restrict__ W1,
                                            const float* __restrict__ W2,
                                            const float* __restrict__ Wout,
                                            short* __restrict__ w1pk,
                                            short* __restrict__ w2pk,
                                            short* __restrict__ wopk,
                                            int* __restrict__ cursor) {
    int id = blockIdx.x * blockDim.x + threadIdx.x;
    if (id < 2048) pack_one(W1, FD, 8, w1pk, id);
    else if (id < 4096) pack_one(W2, FD, 8, w2pk, id - 2048);
    else if (id < 4864) pack_one(Wout, NCLS, 3, wopk, id - 4096);
    else if (id < 4864 + NBIN) cursor[id - 4864] = (id - 4864) * CAPB2;
}

// Kernel T: one-pass dst-bin partition into fixed-capacity segments, payload
// packed as src | (local_dst << 17) (src < 2^17, local < 391 < 2^9) -> 4 B
// per edge. Per-WAVE LDS histograms; one global reservation per (block,bin):
// 391 blocks x 256 bins = 100k atomics spread over 256 addresses (R7's sin
// was 200k on 2 lines + cross-wave LDS contention).
__global__ __launch_bounds__(256) void scatter_k(const int* __restrict__ src,
                                                 const int* __restrict__ dst,
                                                 int* __restrict__ cursor,
                                                 int* __restrict__ ebin) {
    __shared__ int lh[4][NBIN];      // per-wave counts, then per-wave rank cursors
    __shared__ int obase[4][NBIN];   // per-wave write bases
    int t = threadIdx.x, wv = t >> 6;
    int base = blockIdx.x * SBLK;
    for (int i = t; i < 4 * NBIN; i += 256) ((int*)lh)[i] = 0;
    __syncthreads();
    short bins[16]; short locs[16];
    #pragma unroll
    for (int i = 0; i < 16; ++i) {
        int idx = base + t + i * 256;
        int b = -1, loc = 0;
        if (idx < NEDGES) {
            int d = dst[idx];
            b = d / BINW2;
            loc = d - b * BINW2;
            atomicAdd(&lh[wv][b], 1);
        }
        bins[i] = (short)b; locs[i] = (short)loc;
    }
    __syncthreads();
    if (t < NBIN) {
        int c0 = lh[0][t], c1 = lh[1][t], c2 = lh[2][t], c3 = lh[3][t];
        int g = atomicAdd(&cursor[t], c0 + c1 + c2 + c3);
        obase[0][t] = g;
        obase[1][t] = g + c0;
        obase[2][t] = g + c0 + c1;
        obase[3][t] = g + c0 + c1 + c2;
    }
    __syncthreads();
    for (int i = t; i < 4 * NBIN; i += 256) ((int*)lh)[i] = 0;  // rank counters
    __syncthreads();
    #pragma unroll
    for (int i = 0; i < 16; ++i) {
        int idx = base + t + i * 256;
        if (idx < NEDGES) {
            int b = bins[i];
            int r = atomicAdd(&lh[wv][b], 1);
            int pos = obase[wv][b] + r;
            if (pos < (b + 1) * CAPB2)       // statistical OOB guard
                ebin[pos] = src[idx] | ((int)locs[i] << 17);
        }
    }
}

// Kernel B: per-bin counting sort, entirely in LDS. One block owns one bin:
// stage the ~6250 packed edges (32 KB), LDS histogram over 391 local nodes,
// wave-scan -> local rowptr, LDS-rank scatter into a PACKED CSR segment at
// bin*CAPB2 (25 KB, single-CU writer -> coalesced, one write-allocate pass).
// Zero device-scope per-edge atomics (R8's fill_all: 85 us, 83 MB writes).
// Fuses deg/dinv/rowptr production.
__global__ __launch_bounds__(256) void build_bin(const int* __restrict__ ebin,
                                                 const int* __restrict__ cursor,
                                                 int* __restrict__ adj,
                                                 int* __restrict__ rowptr,
                                                 int* __restrict__ degA,
                                                 float* __restrict__ dinv) {
    __shared__ int stage[CAPB2];       // 32 KB
    __shared__ int hist[BINW2 + 1];
    __shared__ int rp[BINW2 + 1];
    int bin = blockIdx.x, t = threadIdx.x;
    int ne = cursor[bin] - bin * CAPB2;
    if (ne > CAPB2) ne = CAPB2;
    for (int i = t; i < ne; i += 256) stage[i] = ebin[bin * CAPB2 + i];
    for (int i = t; i < BINW2 + 1; i += 256) hist[i] = 0;
    __syncthreads();
    for (int i = t; i < ne; i += 256) atomicAdd(&hist[stage[i] >> 17], 1);
    __syncthreads();
    // exclusive scan of hist[0..390] by wave 0 (lane owns 7 counters)
    if (t < 64) {
        int c[7]; int s = 0;
        #pragma unroll
        for (int k = 0; k < 7; ++k) {
            int idx = t * 7 + k;
            c[k] = (idx < BINW2) ? hist[idx] : 0;
            s += c[k];
        }
        int inc = s;
        #pragma unroll
        for (int off = 1; off < 64; off <<= 1) {
            int o = __shfl_up(inc, off);
            if (t >= off) inc += o;
        }
        int excl = inc - s;
        #pragma unroll
        for (int k = 0; k < 7; ++k) {
            int idx = t * 7 + k;
            if (idx < BINW2) { rp[idx] = excl; excl += c[k]; }
        }
    }
    __syncthreads();
    // per-node outputs (coalesced)
    int nbase = bin * BINW2;
    for (int l = t; l < BINW2; l += 256) {
        int node = nbase + l;
        if (node < NNODES) {
            rowptr[node] = bin * CAPB2 + rp[l];
            int dg = hist[l];
            degA[node] = dg;
            dinv[node] = rsqrtf((float)dg + 1.0f);
        }
    }
    __syncthreads();
    for (int i = t; i < BINW2 + 1; i += 256) hist[i] = 0;   // rank counters
    __syncthreads();
    for (int i = t; i < ne; i += 256) {
        int p = stage[i];
        int loc = p >> 17;
        int r = atomicAdd(&hist[loc], 1);
        adj[bin * CAPB2 + rp[loc] + r] = p & 0x1FFFF;
    }
}

// ---------------------------------------------------------------------------
// Kernel G: Y[N,128] = X[N,128] @ W[128,128] via split-bf16 MFMA (hi*hi +
// hi*lo + lo*hi; missing lo*lo ~2^-18 rel). Output FP16 (aggregate payload).
// A layout: A[m=lane&15][k=quad*8+j]; C/D: col=lane&15, row=quad*4+reg.
__global__ __launch_bounds__(256) void gemm_mfma128_h(const float* __restrict__ X,
                                                      const short* __restrict__ Bpk,
                                                      __half* __restrict__ Y) {
    int w = threadIdx.x >> 6, lane = threadIdx.x & 63;
    int quad = lane >> 4, m = lane & 15;
    int row0 = blockIdx.x * 64 + w * 16;
    int arow = row0 + m;
    bool aok = arow < NNODES;
    floatx4 acc[8];
    #pragma unroll
    for (int nt = 0; nt < 8; ++nt) acc[nt] = (floatx4){0.f, 0.f, 0.f, 0.f};
    #pragma unroll
    for (int ko = 0; ko < 4; ++ko) {
        int kbase = ko * 32 + quad * 8;
        float4 a0 = aok ? *(const float4*)(X + (size_t)arow * FD + kbase)
                        : make_float4(0.f, 0.f, 0.f, 0.f);
        float4 a1 = aok ? *(const float4*)(X + (size_t)arow * FD + kbase + 4)
                        : make_float4(0.f, 0.f, 0.f, 0.f);
        float f[8] = {a0.x, a0.y, a0.z, a0.w, a1.x, a1.y, a1.z, a1.w};
        short8 ahi, alo;
        #pragma unroll
        for (int j = 0; j < 8; ++j) {
            unsigned short h = f32_bf16_rn(f[j]);
            ahi[j] = (short)h;
            alo[j] = (short)f32_bf16_rn(f[j] - bf16_f32(h));
        }
        const short* bp = Bpk + (size_t)(ko * 8) * 64 * 16 + (size_t)lane * 16;
        #pragma unroll
        for (int nt = 0; nt < 8; ++nt) {
            short8 bhi = *(const short8*)bp;
            short8 blo = *(const short8*)(bp + 8);
            bp += 64 * 16;
            acc[nt] = __builtin_amdgcn_mfma_f32_16x16x32_bf16(ahi, bhi, acc[nt], 0, 0, 0);
            acc[nt] = __builtin_amdgcn_mfma_f32_16x16x32_bf16(ahi, blo, acc[nt], 0, 0, 0);
            acc[nt] = __builtin_amdgcn_mfma_f32_16x16x32_bf16(alo, bhi, acc[nt], 0, 0, 0);
        }
    }
    #pragma unroll
    for (int r = 0; r < 4; ++r) {
        int rr = row0 + quad * 4 + r;
        if (rr < NNODES) {
            __half* y = Y + (size_t)rr * FD + m;
            #pragma unroll
            for (int nt = 0; nt < 8; ++nt) y[nt * 16] = __float2half(acc[nt][r]);
        }
    }
}

// ---------------------------------------------------------------------------
// Kernel O: OUT[N,40] = H[N,128] @ Wout[128,40] + bout, fp32 in/out, 3 n-tiles.
__global__ __launch_bounds__(256) void gemm_out_mfma(const float* __restrict__ X,
                                                     const short* __restrict__ Bpk,
                                                     const float* __restrict__ bout,
                                                     float* __restrict__ Y) {
    int w = threadIdx.x >> 6, lane = threadIdx.x & 63;
    int quad = lane >> 4, m = lane & 15;
    int row0 = blockIdx.x * 64 + w * 16;
    int arow = row0 + m;
    bool aok = arow < NNODES;
    floatx4 acc[3];
    #pragma unroll
    for (int nt = 0; nt < 3; ++nt) acc[nt] = (floatx4){0.f, 0.f, 0.f, 0.f};
    #pragma unroll
    for (int ko = 0; ko < 4; ++ko) {
        int kbase = ko * 32 + quad * 8;
        float4 a0 = aok ? *(const float4*)(X + (size_t)arow * FD + kbase)
                        : make_float4(0.f, 0.f, 0.f, 0.f);
        float4 a1 = aok ? *(const float4*)(X + (size_t)arow * FD + kbase + 4)
                        : make_float4(0.f, 0.f, 0.f, 0.f);
        float f[8] = {a0.x, a0.y, a0.z, a0.w, a1.x, a1.y, a1.z, a1.w};
        short8 ahi, alo;
        #pragma unroll
        for (int j = 0; j < 8; ++j) {
            unsigned short h = f32_bf16_rn(f[j]);
            ahi[j] = (short)h;
            alo[j] = (short)f32_bf16_rn(f[j] - bf16_f32(h));
        }
        const short* bp = Bpk + (size_t)(ko * 3) * 64 * 16 + (size_t)lane * 16;
        #pragma unroll
        for (int nt = 0; nt < 3; ++nt) {
            short8 bhi = *(const short8*)bp;
            short8 blo = *(const short8*)(bp + 8);
            bp += 64 * 16;
            acc[nt] = __builtin_amdgcn_mfma_f32_16x16x32_bf16(ahi, bhi, acc[nt], 0, 0, 0);
            acc[nt] = __builtin_amdgcn_mfma_f32_16x16x32_bf16(ahi, blo, acc[nt], 0, 0, 0);
            acc[nt] = __builtin_amdgcn_mfma_f32_16x16x32_bf16(alo, bhi, acc[nt], 0, 0, 0);
        }
    }
    #pragma unroll
    for (int r = 0; r < 4; ++r) {
        int rr = row0 + quad * 4 + r;
        if (rr < NNODES) {
            #pragma unroll
            for (int nt = 0; nt < 3; ++nt) {
                int col = nt * 16 + m;
                if (col < NCLS)
                    Y[(size_t)rr * NCLS + col] = acc[nt][r] + bout[col];
            }
        }
    }
}

// ---------------------------------------------------------------------------
// Kernel A: gather aggregation + bias + ReLU, FP16 payload, CSR adjacency
// (contiguous per-node neighbor list; staging reads are coalesced).
// L2-miss-path bound at ~199 MB FETCH; 8 gathers in flight.
__global__ __launch_bounds__(128) void aggregate_h(const int2* __restrict__ XW2,
                                                   const int* __restrict__ rowptr,
                                                   const int* __restrict__ degA,
                                                   const int* __restrict__ adj,
                                                   const float* __restrict__ dinv,
                                                   const float* __restrict__ bias,
                                                   float4* __restrict__ Y4) {
    __shared__ int ssrc[4][DEGCAP];
    __shared__ float scoef[4][DEGCAP];
    int sub  = threadIdx.x >> 5;
    int lane = threadIdx.x & 31;
    int node = blockIdx.x * 4 + sub;
    float di = dinv[node];
    int deg = degA[node];
    if (deg > DEGCAP) deg = DEGCAP;
    int base = rowptr[node];
    for (int j = lane; j < deg; j += 32) {
        int s = adj[base + j];
        ssrc[sub][j] = s;
        scoef[sub][j] = dinv[s] * di;
    }
    __syncthreads();
    float4 b = *(const float4*)(bias + 4 * lane);
    float4 v = h4_to_f4(XW2[(size_t)node * 32 + lane]);
    float sd = di * di;
    float4 acc;
    acc.x = v.x * sd; acc.y = v.y * sd; acc.z = v.z * sd; acc.w = v.w * sd;
    int j = 0;
    for (; j + 7 < deg; j += 8) {           // 8 independent gathers in flight
        int2 p[8];
        float c[8];
        #pragma unroll
        for (int q = 0; q < 8; ++q) {
            p[q] = XW2[(size_t)ssrc[sub][j + q] * 32 + lane];
            c[q] = scoef[sub][j + q];
        }
        #pragma unroll
        for (int q = 0; q < 8; ++q) {
            float4 vq = h4_to_f4(p[q]);
            acc.x = fmaf(vq.x, c[q], acc.x); acc.y = fmaf(vq.y, c[q], acc.y);
            acc.z = fmaf(vq.z, c[q], acc.z); acc.w = fmaf(vq.w, c[q], acc.w);
        }
    }
    for (; j < deg; ++j) {
        float4 v0 = h4_to_f4(XW2[(size_t)ssrc[sub][j] * 32 + lane]);
        float c0 = scoef[sub][j];
        acc.x = fmaf(v0.x, c0, acc.x); acc.y = fmaf(v0.y, c0, acc.y);
        acc.z = fmaf(v0.z, c0, acc.z); acc.w = fmaf(v0.w, c0, acc.w);
    }
    acc.x = fmaxf(acc.x + b.x, 0.f);
    acc.y = fmaxf(acc.y + b.y, 0.f);
    acc.z = fmaxf(acc.z + b.z, 0.f);
    acc.w = fmaxf(acc.w + b.w, 0.f);
    Y4[(size_t)node * 32 + lane] = acc;
}

// ---------------------------------------------------------------------------
extern "C" void kernel_launch(void* const* d_in, const int* in_sizes, int n_in,
                              void* d_out, int out_size, void* d_ws, size_t ws_size,
                              hipStream_t stream) {
    const float* x    = (const float*)d_in[0];
    const int*   ei   = (const int*)d_in[1];     // [2, E] flat: src then dst
    const float* W1   = (const float*)d_in[2];
    const float* b1   = (const float*)d_in[3];
    const float* W2   = (const float*)d_in[4];
    const float* b2   = (const float*)d_in[5];
    const float* Wout = (const float*)d_in[6];
    const float* bout = (const float*)d_in[7];
    float* out = (float*)d_out;

    const int* srcv = ei;
    const int* dstv = ei + NEDGES;

    // workspace layout
    float* bufA   = (float*)d_ws;                        // N*128 f32; ebin overlay pre-gemm1; fp16 XW after
    float* bufB   = bufA + (size_t)NNODES * FD;          // N*128 f32
    int*   adj    = (int*)(bufB + (size_t)NNODES * FD);  // NBIN*CAPB2 ints (8.4 MB)
    int*   rowptr = adj + (size_t)NBIN * CAPB2;          // N ints
    int*   degA   = rowptr + NNODES;                     // N ints
    float* dinv   = (float*)(degA + NNODES);             // N f32
    short* w1pk   = (short*)(dinv + NNODES);             // 2048*16 shorts
    short* w2pk   = w1pk + 2048 * 16;
    short* wopk   = w2pk + 2048 * 16;                    // 768*16 shorts
    int*   cursor = (int*)(wopk + 768 * 16);             // NBIN ints
    int*   ebin   = (int*)bufA;                          // NBIN*CAPB2 ints (8.4 MB), dead after build
    __half* xwh   = (__half*)bufA;

    // prep: pack weights + init segment cursors
    prep<<<20, 256, 0, stream>>>(W1, W2, Wout, w1pk, w2pk, wopk, cursor);

    // one-pass dst-bin partition -> per-bin LDS counting sort -> packed CSR
    scatter_k<<<(NEDGES + SBLK - 1) / SBLK, 256, 0, stream>>>(srcv, dstv, cursor, ebin);
    build_bin<<<NBIN, 256, 0, stream>>>(ebin, cursor, adj, rowptr, degA, dinv);

    const int gblocks = (NNODES + 63) / 64;
    // layer 1
    gemm_mfma128_h<<<gblocks, 256, 0, stream>>>(x, w1pk, xwh);
    aggregate_h<<<NNODES / 4, 128, 0, stream>>>((const int2*)xwh, rowptr, degA,
                                                adj, dinv, b1, (float4*)bufB);
    // layer 2
    gemm_mfma128_h<<<gblocks, 256, 0, stream>>>(bufB, w2pk, xwh);
    aggregate_h<<<NNODES / 4, 128, 0, stream>>>((const int2*)xwh, rowptr, degA,
                                                adj, dinv, b2, (float4*)bufB);
    // head
    gemm_out_mfma<<<gblocks, 256, 0, stream>>>(bufB, wopk, bout, out);
}

// Round 10
// 337.739 us; speedup vs baseline: 1.6437x; 1.0307x over previous
//
#include <hip/hip_runtime.h>
#include <hip/hip_bf16.h>
#include <hip/hip_fp16.h>

#define NNODES 100000
#define NEDGES 1600000
#define FD 128
#define NCLS 40
#define DEGCAP 128                 // staging cap; Poisson(16): P(deg>128) ~ 1e-50
#define NBIN 256                   // dst bins; 391 nodes/bin
#define BINW2 391                  // NBIN*BINW2 = 100096 >= NNODES
#define CAPB2 8192                 // per-bin edge segment (mean 6250)
#define SUBC 1024                  // per-(bin,xcd-group) sub-segment (mean 781, +8.7 sigma)
#define SBLK 4096                  // edges per scatter block

typedef __attribute__((ext_vector_type(8))) short short8;   // 8 bf16 (4 VGPRs)
typedef __attribute__((ext_vector_type(4))) float floatx4;  // MFMA C/D

__device__ __forceinline__ unsigned short f32_bf16_rn(float f) {
    unsigned u = __builtin_bit_cast(unsigned, f);
    u = u + 0x7fffu + ((u >> 16) & 1u);          // round-to-nearest-even
    return (unsigned short)(u >> 16);
}
__device__ __forceinline__ float bf16_f32(unsigned short h) {
    unsigned u = ((unsigned)h) << 16;
    return __builtin_bit_cast(float, u);
}
// 4 packed halves (int2) -> float4
__device__ __forceinline__ float4 h4_to_f4(int2 p) {
    __half2 a = __builtin_bit_cast(__half2, p.x);
    __half2 b = __builtin_bit_cast(__half2, p.y);
    float2 fa = __half22float2(a), fb = __half22float2(b);
    return make_float4(fa.x, fa.y, fb.x, fb.y);
}

// ---------------------------------------------------------------------------
// pack W (K=128 x ncols fp32) into MFMA B-fragment layout, split bf16 hi/lo.
__device__ __forceinline__ void pack_one(const float* __restrict__ W, int ncols,
                                         int nt_count, short* __restrict__ out,
                                         int id) {
    int lane = id & 63;
    int nt = (id >> 6) % nt_count;
    int ko = id / (64 * nt_count);
    int col = nt * 16 + (lane & 15);
    int kbase = ko * 32 + (lane >> 4) * 8;
    short* dst = out + (size_t)id * 16;
    #pragma unroll
    for (int j = 0; j < 8; ++j) {
        float v = (col < ncols) ? W[(size_t)(kbase + j) * ncols + col] : 0.f;
        unsigned short h = f32_bf16_rn(v);
        float r = v - bf16_f32(h);
        dst[j] = (short)h;
        dst[8 + j] = (short)f32_bf16_rn(r);
    }
}

// Kernel P: fused prep — pack 3 weights + init 2048 sub-segment cursors.
// ids: [0,2048) W1, [2048,4096) W2, [4096,4864) Wout, [4864,6912) cursor.
__global__ __launch_bounds__(256) void prep(const float* __restrict__ W1,
                                            const float* __restrict__ W2,
                                            const float* __restrict__ Wout,
                                            short* __restrict__ w1pk,
                                            short* __restrict__ w2pk,
                                            short* __restrict__ wopk,
                                            int* __restrict__ cursor) {
    int id = blockIdx.x * blockDim.x + threadIdx.x;
    if (id < 2048) pack_one(W1, FD, 8, w1pk, id);
    else if (id < 4096) pack_one(W2, FD, 8, w2pk, id - 2048);
    else if (id < 4864) pack_one(Wout, NCLS, 3, wopk, id - 4096);
    else if (id < 6912) {
        int c = id - 4864;                   // c = bin*8 + g
        cursor[c] = (c >> 3) * CAPB2 + (c & 7) * SUBC;
    }
}

// Kernel T: one-pass dst-bin partition. v3 (R9 post-mortem):
//  - loop-1 atomic returns ARE the ranks -> no second LDS histogram pass;
//  - src/loc cached in regs -> no global re-read;
//  - XCD-grouped sub-segments (cursor[bin*8 + blockIdx&7]) -> each write-
//    frontier cache line owned by ONE XCD, killing the cross-XCD dirty-line
//    ping-pong that gave R8's 2.7x write amplification (17.5 MB vs 6.4).
__global__ __launch_bounds__(256) void scatter_k(const int* __restrict__ src,
                                                 const int* __restrict__ dst,
                                                 int* __restrict__ cursor,
                                                 int* __restrict__ ebin) {
    __shared__ int lh[4][NBIN];      // per-wave counts
    __shared__ int obase[4][NBIN];   // per-wave write bases
    int t = threadIdx.x, wv = t >> 6;
    int g = blockIdx.x & 7;          // XCD-group heuristic (perf-only)
    int base = blockIdx.x * SBLK;
    for (int i = t; i < 4 * NBIN; i += 256) ((int*)lh)[i] = 0;
    __syncthreads();
    int pay[16];                     // src | loc<<17, or -1
    unsigned short binv[16], rankv[16];
    #pragma unroll
    for (int i = 0; i < 16; ++i) {
        int idx = base + t + i * 256;
        int b = 0, r = 0, p = -1;
        if (idx < NEDGES) {
            int d = dst[idx];
            b = d / BINW2;
            p = src[idx] | ((d - b * BINW2) << 17);
            r = atomicAdd(&lh[wv][b], 1);
        }
        pay[i] = p; binv[i] = (unsigned short)b; rankv[i] = (unsigned short)r;
    }
    __syncthreads();
    if (t < NBIN) {
        int c0 = lh[0][t], c1 = lh[1][t], c2 = lh[2][t], c3 = lh[3][t];
        int tot = c0 + c1 + c2 + c3;
        int gb = tot ? atomicAdd(&cursor[t * 8 + g], tot) : 0;
        obase[0][t] = gb;
        obase[1][t] = gb + c0;
        obase[2][t] = gb + c0 + c1;
        obase[3][t] = gb + c0 + c1 + c2;
    }
    __syncthreads();
    #pragma unroll
    for (int i = 0; i < 16; ++i) {
        if (pay[i] != -1) {
            int b = binv[i];
            int pos = obase[wv][b] + rankv[i];
            if (pos < b * CAPB2 + (g + 1) * SUBC)   // statistical OOB guard
                ebin[pos] = pay[i];
        }
    }
}

// Kernel B: per-bin counting sort, entirely in LDS. One block owns one bin:
// stage the bin's 8 sub-segments (concatenated), LDS histogram over 391
// local nodes, wave-scan -> rowptr, LDS-rank scatter into packed CSR.
__global__ __launch_bounds__(256) void build_bin(const int* __restrict__ ebin,
                                                 const int* __restrict__ cursor,
                                                 int* __restrict__ adj,
                                                 int* __restrict__ rowptr,
                                                 int* __restrict__ degA,
                                                 float* __restrict__ dinv) {
    __shared__ int stage[CAPB2];       // 32 KB
    __shared__ int hist[BINW2 + 1];
    __shared__ int rp[BINW2 + 1];
    int bin = blockIdx.x, t = threadIdx.x;
    int off = 0;
    #pragma unroll
    for (int x = 0; x < 8; ++x) {
        int sb = bin * CAPB2 + x * SUBC;
        int nex = cursor[bin * 8 + x] - sb;     // uniform across threads
        if (nex > SUBC) nex = SUBC;
        for (int i = t; i < nex; i += 256) stage[off + i] = ebin[sb + i];
        off += nex;
    }
    int ne = off;
    for (int i = t; i < BINW2 + 1; i += 256) hist[i] = 0;
    __syncthreads();
    for (int i = t; i < ne; i += 256) atomicAdd(&hist[stage[i] >> 17], 1);
    __syncthreads();
    // exclusive scan of hist[0..390] by wave 0 (lane owns 7 counters)
    if (t < 64) {
        int c[7]; int s = 0;
        #pragma unroll
        for (int k = 0; k < 7; ++k) {
            int idx = t * 7 + k;
            c[k] = (idx < BINW2) ? hist[idx] : 0;
            s += c[k];
        }
        int inc = s;
        #pragma unroll
        for (int o = 1; o < 64; o <<= 1) {
            int v = __shfl_up(inc, o);
            if (t >= o) inc += v;
        }
        int excl = inc - s;
        #pragma unroll
        for (int k = 0; k < 7; ++k) {
            int idx = t * 7 + k;
            if (idx < BINW2) { rp[idx] = excl; excl += c[k]; }
        }
    }
    __syncthreads();
    int nbase = bin * BINW2;
    for (int l = t; l < BINW2; l += 256) {
        int node = nbase + l;
        if (node < NNODES) {
            rowptr[node] = bin * CAPB2 + rp[l];
            int dg = hist[l];
            degA[node] = dg;
            dinv[node] = rsqrtf((float)dg + 1.0f);
        }
    }
    __syncthreads();
    for (int i = t; i < BINW2 + 1; i += 256) hist[i] = 0;   // rank counters
    __syncthreads();
    for (int i = t; i < ne; i += 256) {
        int p = stage[i];
        int loc = p >> 17;
        int r = atomicAdd(&hist[loc], 1);
        adj[bin * CAPB2 + rp[loc] + r] = p & 0x1FFFF;
    }
}

// ---------------------------------------------------------------------------
// Kernel G1: Y[N,128] = X[N,128](fp32) @ W via split-bf16 MFMA, out FP16.
// A layout: A[m=lane&15][k=quad*8+j]; C/D: col=lane&15, row=quad*4+reg.
__global__ __launch_bounds__(256) void gemm_mfma128_h(const float* __restrict__ X,
                                                      const short* __restrict__ Bpk,
                                                      __half* __restrict__ Y) {
    int w = threadIdx.x >> 6, lane = threadIdx.x & 63;
    int quad = lane >> 4, m = lane & 15;
    int row0 = blockIdx.x * 64 + w * 16;
    int arow = row0 + m;
    bool aok = arow < NNODES;
    floatx4 acc[8];
    #pragma unroll
    for (int nt = 0; nt < 8; ++nt) acc[nt] = (floatx4){0.f, 0.f, 0.f, 0.f};
    #pragma unroll
    for (int ko = 0; ko < 4; ++ko) {
        int kbase = ko * 32 + quad * 8;
        float4 a0 = aok ? *(const float4*)(X + (size_t)arow * FD + kbase)
                        : make_float4(0.f, 0.f, 0.f, 0.f);
        float4 a1 = aok ? *(const float4*)(X + (size_t)arow * FD + kbase + 4)
                        : make_float4(0.f, 0.f, 0.f, 0.f);
        float f[8] = {a0.x, a0.y, a0.z, a0.w, a1.x, a1.y, a1.z, a1.w};
        short8 ahi, alo;
        #pragma unroll
        for (int j = 0; j < 8; ++j) {
            unsigned short h = f32_bf16_rn(f[j]);
            ahi[j] = (short)h;
            alo[j] = (short)f32_bf16_rn(f[j] - bf16_f32(h));
        }
        const short* bp = Bpk + (size_t)(ko * 8) * 64 * 16 + (size_t)lane * 16;
        #pragma unroll
        for (int nt = 0; nt < 8; ++nt) {
            short8 bhi = *(const short8*)bp;
            short8 blo = *(const short8*)(bp + 8);
            bp += 64 * 16;
            acc[nt] = __builtin_amdgcn_mfma_f32_16x16x32_bf16(ahi, bhi, acc[nt], 0, 0, 0);
            acc[nt] = __builtin_amdgcn_mfma_f32_16x16x32_bf16(ahi, blo, acc[nt], 0, 0, 0);
            acc[nt] = __builtin_amdgcn_mfma_f32_16x16x32_bf16(alo, bhi, acc[nt], 0, 0, 0);
        }
    }
    #pragma unroll
    for (int r = 0; r < 4; ++r) {
        int rr = row0 + quad * 4 + r;
        if (rr < NNODES) {
            __half* y = Y + (size_t)rr * FD + m;
            #pragma unroll
            for (int nt = 0; nt < 8; ++nt) y[nt * 16] = __float2half(acc[nt][r]);
        }
    }
}

// Kernel G2: same but A input FP16 (activations are fp16 end-to-end now).
__global__ __launch_bounds__(256) void gemm_mfma128_hh(const __half* __restrict__ X,
                                                       const short* __restrict__ Bpk,
                                                       __half* __restrict__ Y) {
    int w = threadIdx.x >> 6, lane = threadIdx.x & 63;
    int quad = lane >> 4, m = lane & 15;
    int row0 = blockIdx.x * 64 + w * 16;
    int arow = row0 + m;
    bool aok = arow < NNODES;
    floatx4 acc[8];
    #pragma unroll
    for (int nt = 0; nt < 8; ++nt) acc[nt] = (floatx4){0.f, 0.f, 0.f, 0.f};
    #pragma unroll
    for (int ko = 0; ko < 4; ++ko) {
        int kbase = ko * 32 + quad * 8;
        int4 ar = aok ? *(const int4*)(X + (size_t)arow * FD + kbase)
                      : make_int4(0, 0, 0, 0);
        float4 fa = h4_to_f4(make_int2(ar.x, ar.y));
        float4 fb = h4_to_f4(make_int2(ar.z, ar.w));
        float f[8] = {fa.x, fa.y, fa.z, fa.w, fb.x, fb.y, fb.z, fb.w};
        short8 ahi, alo;
        #pragma unroll
        for (int j = 0; j < 8; ++j) {
            unsigned short h = f32_bf16_rn(f[j]);
            ahi[j] = (short)h;
            alo[j] = (short)f32_bf16_rn(f[j] - bf16_f32(h));
        }
        const short* bp = Bpk + (size_t)(ko * 8) * 64 * 16 + (size_t)lane * 16;
        #pragma unroll
        for (int nt = 0; nt < 8; ++nt) {
            short8 bhi = *(const short8*)bp;
            short8 blo = *(const short8*)(bp + 8);
            bp += 64 * 16;
            acc[nt] = __builtin_amdgcn_mfma_f32_16x16x32_bf16(ahi, bhi, acc[nt], 0, 0, 0);
            acc[nt] = __builtin_amdgcn_mfma_f32_16x16x32_bf16(ahi, blo, acc[nt], 0, 0, 0);
            acc[nt] = __builtin_amdgcn_mfma_f32_16x16x32_bf16(alo, bhi, acc[nt], 0, 0, 0);
        }
    }
    #pragma unroll
    for (int r = 0; r < 4; ++r) {
        int rr = row0 + quad * 4 + r;
        if (rr < NNODES) {
            __half* y = Y + (size_t)rr * FD + m;
            #pragma unroll
            for (int nt = 0; nt < 8; ++nt) y[nt * 16] = __float2half(acc[nt][r]);
        }
    }
}

// Kernel O: OUT[N,40] = H[N,128](fp16) @ Wout + bout, fp32 out, 3 n-tiles.
__global__ __launch_bounds__(256) void gemm_out_mfma_h(const __half* __restrict__ X,
                                                       const short* __restrict__ Bpk,
                                                       const float* __restrict__ bout,
                                                       float* __restrict__ Y) {
    int w = threadIdx.x >> 6, lane = threadIdx.x & 63;
    int quad = lane >> 4, m = lane & 15;
    int row0 = blockIdx.x * 64 + w * 16;
    int arow = row0 + m;
    bool aok = arow < NNODES;
    floatx4 acc[3];
    #pragma unroll
    for (int nt = 0; nt < 3; ++nt) acc[nt] = (floatx4){0.f, 0.f, 0.f, 0.f};
    #pragma unroll
    for (int ko = 0; ko < 4; ++ko) {
        int kbase = ko * 32 + quad * 8;
        int4 ar = aok ? *(const int4*)(X + (size_t)arow * FD + kbase)
                      : make_int4(0, 0, 0, 0);
        float4 fa = h4_to_f4(make_int2(ar.x, ar.y));
        float4 fb = h4_to_f4(make_int2(ar.z, ar.w));
        float f[8] = {fa.x, fa.y, fa.z, fa.w, fb.x, fb.y, fb.z, fb.w};
        short8 ahi, alo;
        #pragma unroll
        for (int j = 0; j < 8; ++j) {
            unsigned short h = f32_bf16_rn(f[j]);
            ahi[j] = (short)h;
            alo[j] = (short)f32_bf16_rn(f[j] - bf16_f32(h));
        }
        const short* bp = Bpk + (size_t)(ko * 3) * 64 * 16 + (size_t)lane * 16;
        #pragma unroll
        for (int nt = 0; nt < 3; ++nt) {
            short8 bhi = *(const short8*)bp;
            short8 blo = *(const short8*)(bp + 8);
            bp += 64 * 16;
            acc[nt] = __builtin_amdgcn_mfma_f32_16x16x32_bf16(ahi, bhi, acc[nt], 0, 0, 0);
            acc[nt] = __builtin_amdgcn_mfma_f32_16x16x32_bf16(ahi, blo, acc[nt], 0, 0, 0);
            acc[nt] = __builtin_amdgcn_mfma_f32_16x16x32_bf16(alo, bhi, acc[nt], 0, 0, 0);
        }
    }
    #pragma unroll
    for (int r = 0; r < 4; ++r) {
        int rr = row0 + quad * 4 + r;
        if (rr < NNODES) {
            #pragma unroll
            for (int nt = 0; nt < 3; ++nt) {
                int col = nt * 16 + m;
                if (col < NCLS)
                    Y[(size_t)rr * NCLS + col] = acc[nt][r] + bout[col];
            }
        }
    }
}

// ---------------------------------------------------------------------------
// Kernel A: gather aggregation + bias + ReLU; FP16 in AND out (out feeds the
// fp16-A gemms). L2-miss-path bound (~199 MB compulsory per-XCD XW traffic).
__global__ __launch_bounds__(128) void aggregate_h(const int2* __restrict__ XW2,
                                                   const int* __restrict__ rowptr,
                                                   const int* __restrict__ degA,
                                                   const int* __restrict__ adj,
                                                   const float* __restrict__ dinv,
                                                   const float* __restrict__ bias,
                                                   int2* __restrict__ Yh) {
    __shared__ int ssrc[4][DEGCAP];
    __shared__ float scoef[4][DEGCAP];
    int sub  = threadIdx.x >> 5;
    int lane = threadIdx.x & 31;
    int node = blockIdx.x * 4 + sub;
    float di = dinv[node];
    int deg = degA[node];
    if (deg > DEGCAP) deg = DEGCAP;
    int base = rowptr[node];
    for (int j = lane; j < deg; j += 32) {
        int s = adj[base + j];
        ssrc[sub][j] = s;
        scoef[sub][j] = dinv[s] * di;
    }
    __syncthreads();
    float4 b = *(const float4*)(bias + 4 * lane);
    float4 v = h4_to_f4(XW2[(size_t)node * 32 + lane]);
    float sd = di * di;
    float4 acc;
    acc.x = v.x * sd; acc.y = v.y * sd; acc.z = v.z * sd; acc.w = v.w * sd;
    int j = 0;
    for (; j + 7 < deg; j += 8) {           // 8 independent gathers in flight
        int2 p[8];
        float c[8];
        #pragma unroll
        for (int q = 0; q < 8; ++q) {
            p[q] = XW2[(size_t)ssrc[sub][j + q] * 32 + lane];
            c[q] = scoef[sub][j + q];
        }
        #pragma unroll
        for (int q = 0; q < 8; ++q) {
            float4 vq = h4_to_f4(p[q]);
            acc.x = fmaf(vq.x, c[q], acc.x); acc.y = fmaf(vq.y, c[q], acc.y);
            acc.z = fmaf(vq.z, c[q], acc.z); acc.w = fmaf(vq.w, c[q], acc.w);
        }
    }
    for (; j < deg; ++j) {
        float4 v0 = h4_to_f4(XW2[(size_t)ssrc[sub][j] * 32 + lane]);
        float c0 = scoef[sub][j];
        acc.x = fmaf(v0.x, c0, acc.x); acc.y = fmaf(v0.y, c0, acc.y);
        acc.z = fmaf(v0.z, c0, acc.z); acc.w = fmaf(v0.w, c0, acc.w);
    }
    __half2 h01 = __floats2half2_rn(fmaxf(acc.x + b.x, 0.f), fmaxf(acc.y + b.y, 0.f));
    __half2 h23 = __floats2half2_rn(fmaxf(acc.z + b.z, 0.f), fmaxf(acc.w + b.w, 0.f));
    Yh[(size_t)node * 32 + lane] = make_int2(__builtin_bit_cast(int, h01),
                                             __builtin_bit_cast(int, h23));
}

// ---------------------------------------------------------------------------
extern "C" void kernel_launch(void* const* d_in, const int* in_sizes, int n_in,
                              void* d_out, int out_size, void* d_ws, size_t ws_size,
                              hipStream_t stream) {
    const float* x    = (const float*)d_in[0];
    const int*   ei   = (const int*)d_in[1];     // [2, E] flat: src then dst
    const float* W1   = (const float*)d_in[2];
    const float* b1   = (const float*)d_in[3];
    const float* W2   = (const float*)d_in[4];
    const float* b2   = (const float*)d_in[5];
    const float* Wout = (const float*)d_in[6];
    const float* bout = (const float*)d_in[7];
    float* out = (float*)d_out;

    const int* srcv = ei;
    const int* dstv = ei + NEDGES;

    // workspace layout
    float* bufA   = (float*)d_ws;                        // 51.2 MB slot: ebin overlay pre-gemm1; fp16 XW after
    float* bufB   = bufA + (size_t)NNODES * FD;          // slot used as fp16 activations
    int*   adj    = (int*)(bufB + (size_t)NNODES * FD);  // NBIN*CAPB2 ints (8.4 MB)
    int*   rowptr = adj + (size_t)NBIN * CAPB2;          // N ints
    int*   degA   = rowptr + NNODES;                     // N ints
    float* dinv   = (float*)(degA + NNODES);             // N f32
    short* w1pk   = (short*)(dinv + NNODES);             // 2048*16 shorts
    short* w2pk   = w1pk + 2048 * 16;
    short* wopk   = w2pk + 2048 * 16;                    // 768*16 shorts
    int*   cursor = (int*)(wopk + 768 * 16);             // NBIN*8 ints
    int*   ebin   = (int*)bufA;                          // NBIN*CAPB2 ints, dead after build
    __half* xwh   = (__half*)bufA;                       // fp16 XW (gemm out / gather payload)
    __half* acth  = (__half*)bufB;                       // fp16 activations (aggregate out)

    // prep: pack weights + init sub-segment cursors
    prep<<<27, 256, 0, stream>>>(W1, W2, Wout, w1pk, w2pk, wopk, cursor);

    // one-pass dst-bin partition -> per-bin LDS counting sort -> packed CSR
    scatter_k<<<(NEDGES + SBLK - 1) / SBLK, 256, 0, stream>>>(srcv, dstv, cursor, ebin);
    build_bin<<<NBIN, 256, 0, stream>>>(ebin, cursor, adj, rowptr, degA, dinv);

    const int gblocks = (NNODES + 63) / 64;
    // layer 1
    gemm_mfma128_h<<<gblocks, 256, 0, stream>>>(x, w1pk, xwh);
    aggregate_h<<<NNODES / 4, 128, 0, stream>>>((const int2*)xwh, rowptr, degA,
                                                adj, dinv, b1, (int2*)acth);
    // layer 2
    gemm_mfma128_hh<<<gblocks, 256, 0, stream>>>(acth, w2pk, xwh);
    aggregate_h<<<NNODES / 4, 128, 0, stream>>>((const int2*)xwh, rowptr, degA,
                                                adj, dinv, b2, (int2*)acth);
    // head
    gemm_out_mfma_h<<<gblocks, 256, 0, stream>>>(acth, wopk, bout, out);
}